// Round 16
// baseline (416.448 us; speedup 1.0000x reference)
//
#include <hip/hip_runtime.h>
#include <hip/hip_bf16.h>
#include <math.h>

typedef short bf16x8 __attribute__((ext_vector_type(8)));
typedef short bf16x4 __attribute__((ext_vector_type(4)));
typedef float f32x4 __attribute__((ext_vector_type(4)));

__device__ inline unsigned short f2bf(float f) {
  unsigned u = __float_as_uint(f);
  u += 0x7FFF + ((u >> 16) & 1);           // RNE
  return (unsigned short)(u >> 16);
}
__device__ inline float bf2f(unsigned short h) {
  return __uint_as_float(((unsigned)h) << 16);
}

// ---------------- CSR build ----------------

__global__ __launch_bounds__(256) void count_k(const int* __restrict__ dst, int* __restrict__ cnt, int e) {
  int i = blockIdx.x * 256 + threadIdx.x;
  if (i < e) atomicAdd(&cnt[dst[i]], 1);
}

__global__ __launch_bounds__(256) void scan_a(const int* __restrict__ cnt, int* __restrict__ bsum, int n) {
  int i = blockIdx.x * 256 + threadIdx.x;
  int v = (i < n) ? cnt[i] : 0;
#pragma unroll
  for (int o = 32; o > 0; o >>= 1) v += __shfl_xor(v, o);
  __shared__ int ws[4];
  if ((threadIdx.x & 63) == 0) ws[threadIdx.x >> 6] = v;
  __syncthreads();
  if (threadIdx.x == 0) bsum[blockIdx.x] = ws[0] + ws[1] + ws[2] + ws[3];
}

__global__ __launch_bounds__(256) void scan_b(const int* __restrict__ bsum, int* __restrict__ bpre,
                                              int* __restrict__ off_n, int nb) {
  __shared__ int s[256];
  int t = threadIdx.x;
  int v = (t < nb) ? bsum[t] : 0;
  s[t] = v;
  __syncthreads();
  for (int o = 1; o < 256; o <<= 1) {
    int u = (t >= o) ? s[t - o] : 0;
    __syncthreads();
    s[t] += u;
    __syncthreads();
  }
  if (t < nb) bpre[t] = s[t] - v;
  if (t == 255) off_n[0] = s[255];
}

// scan_c also computes dis = rsqrt(cnt+1)
__global__ __launch_bounds__(256) void scan_c(const int* __restrict__ cnt, const int* __restrict__ bpre,
                                              int* __restrict__ off, int* __restrict__ cursor,
                                              float* __restrict__ dis, int n) {
  __shared__ int s[256];
  int i = blockIdx.x * 256 + threadIdx.x;
  int t = threadIdx.x;
  int v = (i < n) ? cnt[i] : 0;
  s[t] = v;
  __syncthreads();
  for (int o = 1; o < 256; o <<= 1) {
    int u = (t >= o) ? s[t - o] : 0;
    __syncthreads();
    s[t] += u;
    __syncthreads();
  }
  if (i < n) {
    int ov = bpre[blockIdx.x] + s[t] - v;
    off[i] = ov;
    cursor[i] = ov;
    dis[i] = rsqrtf((float)v + 1.0f);
  }
}

__global__ __launch_bounds__(256) void scatter_k(const int* __restrict__ src, const int* __restrict__ dst,
                                                 int* __restrict__ cursor, int* __restrict__ csr, int e) {
  int i = blockIdx.x * 256 + threadIdx.x;
  if (i < e) {
    int p = atomicAdd(&cursor[dst[i]], 1);
    csr[p] = src[i];
  }
}

// ------- weight convert: W[K][N] fp32 -> Wc[N][K] bf16 -------

__global__ __launch_bounds__(256) void wconv_k(const float* __restrict__ W1, const float* __restrict__ Wr,
                                               const float* __restrict__ W2, const float* __restrict__ W3,
                                               const float* __restrict__ W4,
                                               short* __restrict__ o1, short* __restrict__ oR,
                                               short* __restrict__ o2, short* __restrict__ o3,
                                               short* __restrict__ o4) {
  int b = blockIdx.x;  // 960 rows total
  const float* W; short* O; int K, N, nr;
  if (b < 64)       { W = W1; O = o1; K = 128; N = 64;  nr = b; }
  else if (b < 128) { W = Wr; O = oR; K = 128; N = 64;  nr = b - 64; }
  else if (b < 384) { W = W2; O = o2; K = 64;  N = 256; nr = b - 128; }
  else if (b < 896) { W = W3; O = o3; K = 256; N = 512; nr = b - 384; }
  else              { W = W4; O = o4; K = 512; N = 64;  nr = b - 896; }
  for (int k = threadIdx.x; k < K; k += 256)
    O[(size_t)nr * K + k] = (short)f2bf(W[(size_t)k * N + nr]);
}

// ------- MFMA GEMM (generic): C[M,NTOT] = A[M,KT] @ Wc[NTOT,KT](bf16) -------

template<int KT, int NTOT, int WM, int WN, int BIAS, int RELU, int ABF, int OBF, int SPLIT, int SCL, int BLK>
__global__ __launch_bounds__(256, BLK) void mgemm(const void* __restrict__ Av,
                                                  const short* __restrict__ Wc,
                                                  const float* __restrict__ bias,
                                                  void* __restrict__ Cv, void* __restrict__ Cv2,
                                                  const float* __restrict__ scl, int M) {
  __shared__ short As[64 * WM][ABF ? 40 : 72];
  __shared__ short Bs[64 * WN][40];
  const int tid = threadIdx.x;
  const int row0 = blockIdx.x * (64 * WM);
  const int col0 = blockIdx.y * (64 * WN);
  const int w = tid >> 6, lane = tid & 63;
  const int wm = w / WN, wn = w % WN;
  const int rm = wm * 64, cn = wn * 64;
  const int lm = lane & 15, lk = (lane >> 4) * 8;

  f32x4 acc[4][4];
#pragma unroll
  for (int i = 0; i < 4; i++)
#pragma unroll
    for (int j = 0; j < 4; j++)
#pragma unroll
      for (int r = 0; r < 4; r++) acc[i][j][r] = 0.f;

  for (int k0 = 0; k0 < KT; k0 += 32) {
#pragma unroll
    for (int p = 0; p < WM; p++) {
      int r = (tid >> 2) + p * 64;
      int kseg = (tid & 3) * 8;
      int gr = row0 + r;
      if (ABF) {
        bf16x8 v = {0, 0, 0, 0, 0, 0, 0, 0};
        if (gr < M) v = *(const bf16x8*)((const short*)Av + (size_t)gr * KT + k0 + kseg);
        *(bf16x8*)&As[r][kseg] = v;
      } else {
        float4 v0 = {0.f, 0.f, 0.f, 0.f}, v1 = {0.f, 0.f, 0.f, 0.f};
        if (gr < M) {
          const float* ap = (const float*)Av + (size_t)gr * KT + k0 + kseg;
          v0 = *(const float4*)ap;
          v1 = *(const float4*)(ap + 4);
        }
        float vv[8] = {v0.x, v0.y, v0.z, v0.w, v1.x, v1.y, v1.z, v1.w};
        bf16x8 hv, lv;
#pragma unroll
        for (int j = 0; j < 8; j++) {
          unsigned short h = f2bf(vv[j]);
          hv[j] = (short)h;
          lv[j] = (short)f2bf(vv[j] - bf2f(h));
        }
        *(bf16x8*)&As[r][kseg] = hv;
        *(bf16x8*)&As[r][32 + kseg] = lv;
      }
    }
#pragma unroll
    for (int p = 0; p < WN; p++) {
      int nr = (tid >> 2) + p * 64;
      int seg = (tid & 3) * 8;
      *(bf16x8*)&Bs[nr][seg] = *(const bf16x8*)(Wc + (size_t)(col0 + nr) * KT + k0 + seg);
    }
    __syncthreads();

    bf16x8 ah[4], al[4], bb[4];
#pragma unroll
    for (int mt = 0; mt < 4; mt++) {
      ah[mt] = *(const bf16x8*)&As[rm + mt * 16 + lm][lk];
      if (!ABF) al[mt] = *(const bf16x8*)&As[rm + mt * 16 + lm][32 + lk];
    }
#pragma unroll
    for (int nt = 0; nt < 4; nt++) bb[nt] = *(const bf16x8*)&Bs[cn + nt * 16 + lm][lk];
#pragma unroll
    for (int mt = 0; mt < 4; mt++)
#pragma unroll
      for (int nt = 0; nt < 4; nt++) {
        acc[mt][nt] = __builtin_amdgcn_mfma_f32_16x16x32_bf16(ah[mt], bb[nt], acc[mt][nt], 0, 0, 0);
        if (!ABF)
          acc[mt][nt] = __builtin_amdgcn_mfma_f32_16x16x32_bf16(al[mt], bb[nt], acc[mt][nt], 0, 0, 0);
      }
    __syncthreads();
  }

  if (SPLIT) {
    short* epi = (short*)&As[0][0];   // 128*64 shorts = 16 KB
    if (wn == 0) {
#pragma unroll
      for (int mt = 0; mt < 4; mt++) {
        int lr = rm + mt * 16 + (lane >> 4) * 4;
#pragma unroll
        for (int r = 0; r < 4; r++) {
          int gr = row0 + lr + r;
          float sc = (SCL && gr < M) ? scl[gr] : 0.f;
#pragma unroll
          for (int nt = 0; nt < 4; nt++)
            epi[(lr + r) * 64 + nt * 16 + lm] = (short)f2bf(acc[mt][nt][r] * sc);
        }
      }
    } else {
#pragma unroll
      for (int mt = 0; mt < 4; mt++) {
        int grb = row0 + rm + mt * 16 + (lane >> 4) * 4;
#pragma unroll
        for (int nt = 0; nt < 4; nt++) {
          int gc = nt * 16 + lm;
          float bv = bias[gc];
#pragma unroll
          for (int r = 0; r < 4; r++) {
            int gr = grb + r;
            if (gr < M) ((float*)Cv2)[(size_t)gr * 64 + gc] = acc[mt][nt][r] + bv;
          }
        }
      }
    }
    __syncthreads();
    int base = tid * 32;
    int row = base >> 6, col = base & 63;
    int gr = row0 + row;
    if (gr < M) {
#pragma unroll
      for (int q = 0; q < 4; q++)
        *(bf16x8*)((short*)Cv + (size_t)gr * 64 + col + q * 8) = *(bf16x8*)&epi[base + q * 8];
    }
  } else if (OBF && WM == 1) {
    short* epi = &Bs[0][0];
    const int NCOL = 64 * WN;
    float bvv[4];
#pragma unroll
    for (int nt = 0; nt < 4; nt++) bvv[nt] = BIAS ? bias[col0 + cn + nt * 16 + lm] : 0.f;
#pragma unroll
    for (int mt = 0; mt < 4; mt++) {
      __syncthreads();
#pragma unroll
      for (int r = 0; r < 4; r++) {
        int gr = row0 + mt * 16 + (lane >> 4) * 4 + r;
        float sc = (SCL && gr < M) ? scl[gr] : 1.f;
#pragma unroll
        for (int nt = 0; nt < 4; nt++) {
          float v = acc[mt][nt][r] + bvv[nt];
          if (RELU) v = (v >= 0.f) ? v : 0.01f * v;
          if (SCL) v *= sc;
          epi[((lane >> 4) * 4 + r) * NCOL + cn + nt * 16 + lm] = (short)f2bf(v);
        }
      }
      __syncthreads();
      const int per = (16 * NCOL) / 256;
      int base = tid * per;
      int lr = base / NCOL, lc = base % NCOL;
      int gr = row0 + mt * 16 + lr;
      if (gr < M) {
#pragma unroll
        for (int q = 0; q < per / 8; q++)
          *(bf16x8*)((short*)Cv + (size_t)gr * NTOT + col0 + lc + q * 8) = *(bf16x8*)&epi[base + q * 8];
      }
    }
  } else {
#pragma unroll
    for (int mt = 0; mt < 4; mt++) {
      int grb = row0 + rm + mt * 16 + (lane >> 4) * 4;
#pragma unroll
      for (int nt = 0; nt < 4; nt++) {
        int gc = col0 + cn + nt * 16 + lm;
        float bv = BIAS ? bias[gc] : 0.f;
#pragma unroll
        for (int r = 0; r < 4; r++) {
          int gr = grb + r;
          if (gr < M) {
            float v = acc[mt][nt][r] + bv;
            if (RELU) v = (v >= 0.f) ? v : 0.01f * v;
            if (SCL) v *= scl[gr];
            if (OBF) ((short*)Cv)[(size_t)gr * NTOT + gc] = (short)f2bf(v);
            else     ((float*)Cv)[(size_t)gr * NTOT + gc] = v;
          }
        }
      }
    }
  }
}

// ------- fused layer3+layer4 (R16): BARRIER-FREE. t4b = bf16(dis*(leaky(z3@W3+b3)@W4)) -------
// 128 rows/block, wave w owns m-tiles {w, 4+w} (rows w*16.. and 64+w*16..).
// W3/W4 B-fragments read directly from global (L2-resident); Hs + epilogue staging
// are wave-private LDS regions -> zero __syncthreads, waves fully independent.

__global__ __launch_bounds__(256, 2) void fused34_k(const short* __restrict__ z3,
                                                    const short* __restrict__ W3c,  // [512][256] bf16
                                                    const float* __restrict__ b3,
                                                    const short* __restrict__ W4c,  // [64][512] bf16
                                                    const float* __restrict__ dis,
                                                    short* __restrict__ T4, int M) {
  __shared__ short epi[4][2048];   // per-wave: Hs (2x16x40) during chunks, 32x64 at epilogue
  const int tid = threadIdx.x;
  const int row0 = blockIdx.x * 128;
  const int w = tid >> 6, lane = tid & 63;
  const int lm = lane & 15, lk = (lane >> 4) * 8;
  const int rquad = (lane >> 4) * 4;
  short* Hs = &epi[w][0];

  // z3 A-fragments in registers: 2 m-tiles x full K=256 (64 VGPR)
  bf16x8 afr[2][8];
#pragma unroll
  for (int mt = 0; mt < 2; mt++) {
    int gr = row0 + mt * 64 + w * 16 + lm;
    bool ok = gr < M;
    const short* zp = z3 + (size_t)gr * 256 + lk;
#pragma unroll
    for (int kc = 0; kc < 8; kc++) {
      bf16x8 v = {0, 0, 0, 0, 0, 0, 0, 0};
      if (ok) v = *(const bf16x8*)(zp + kc * 32);
      afr[mt][kc] = v;
    }
  }

  f32x4 t4acc[2][4];
#pragma unroll
  for (int mt = 0; mt < 2; mt++)
#pragma unroll
    for (int nt = 0; nt < 4; nt++)
#pragma unroll
      for (int r = 0; r < 4; r++) t4acc[mt][nt][r] = 0.f;

  for (int c = 0; c < 16; c++) {
    // stage-1: h3 chunk (32 cols) for both m-tiles; B direct from L2
    f32x4 acc1[2][2];
#pragma unroll
    for (int mt = 0; mt < 2; mt++)
#pragma unroll
      for (int nt = 0; nt < 2; nt++)
#pragma unroll
        for (int r = 0; r < 4; r++) acc1[mt][nt][r] = 0.f;
#pragma unroll
    for (int k0 = 0; k0 < 8; k0++) {
      bf16x8 bb[2];
#pragma unroll
      for (int nt = 0; nt < 2; nt++)
        bb[nt] = *(const bf16x8*)(W3c + (size_t)(c * 32 + nt * 16 + lm) * 256 + k0 * 32 + lk);
#pragma unroll
      for (int mt = 0; mt < 2; mt++)
#pragma unroll
        for (int nt = 0; nt < 2; nt++)
          acc1[mt][nt] = __builtin_amdgcn_mfma_f32_16x16x32_bf16(afr[mt][k0], bb[nt], acc1[mt][nt], 0, 0, 0);
    }
    // bias + leaky -> bf16 -> Hs (wave-private; C->A layout)
#pragma unroll
    for (int nt = 0; nt < 2; nt++) {
      float bv = b3[c * 32 + nt * 16 + lm];
#pragma unroll
      for (int mt = 0; mt < 2; mt++)
#pragma unroll
        for (int r = 0; r < 4; r++) {
          float v = acc1[mt][nt][r] + bv;
          v = (v >= 0.f) ? v : 0.01f * v;
          Hs[mt * 640 + (rquad + r) * 40 + nt * 16 + lm] = (short)f2bf(v);
        }
    }
    // stage-2: t4 += h3_chunk @ W4_chunk (W4 direct from L2)
    bf16x8 bb2[4];
#pragma unroll
    for (int nt = 0; nt < 4; nt++)
      bb2[nt] = *(const bf16x8*)(W4c + (size_t)(nt * 16 + lm) * 512 + c * 32 + lk);
#pragma unroll
    for (int mt = 0; mt < 2; mt++) {
      bf16x8 ah2 = *(const bf16x8*)&Hs[mt * 640 + lm * 40 + lk];
#pragma unroll
      for (int nt = 0; nt < 4; nt++)
        t4acc[mt][nt] = __builtin_amdgcn_mfma_f32_16x16x32_bf16(ah2, bb2[nt], t4acc[mt][nt], 0, 0, 0);
    }
  }

  // epilogue: bf16 t4 = acc*dis, wave-private staging, coalesced 64B/lane stores
#pragma unroll
  for (int mt = 0; mt < 2; mt++)
#pragma unroll
    for (int r = 0; r < 4; r++) {
      int gr = row0 + mt * 64 + w * 16 + rquad + r;
      float sc = (gr < M) ? dis[gr] : 0.f;
#pragma unroll
      for (int nt = 0; nt < 4; nt++)
        Hs[mt * 1024 + (rquad + r) * 64 + nt * 16 + lm] = (short)f2bf(t4acc[mt][nt][r] * sc);
    }
  {
    int base = lane * 32;                 // 2048 shorts / 64 lanes
    int mt = lane >> 5, row = (lane >> 1) & 15, col = (lane & 1) * 32;
    int gr = row0 + mt * 64 + w * 16 + row;
    if (gr < M) {
#pragma unroll
      for (int q = 0; q < 4; q++)
        *(bf16x8*)(T4 + (size_t)gr * 64 + col + q * 8) = *(bf16x8*)&Hs[base + q * 8];
    }
  }
}

// ---------------- Aggregation (dis-free; rows pre-scaled by dis) ----------------

template<int BR, int OSCL>
__global__ __launch_bounds__(256) void aggb64_k(const short* __restrict__ T, const float* __restrict__ dis,
                                                const int* __restrict__ off, const int* __restrict__ csr,
                                                const float* __restrict__ bias, short* __restrict__ Out, int n) {
  int wid = (blockIdx.x * 256 + threadIdx.x) >> 6;
  int lane = threadIdx.x & 63;
  if (wid >= n) return;
  float di = dis[wid];
  int e0 = off[wid], e1 = off[wid + 1];
  float acc = bf2f((unsigned short)T[(size_t)wid * 64 + lane]);
  int e = e0;
  for (; e + 8 <= e1; e += 8) {
    int j0 = csr[e], j1 = csr[e + 1], j2 = csr[e + 2], j3 = csr[e + 3];
    int j4 = csr[e + 4], j5 = csr[e + 5], j6 = csr[e + 6], j7 = csr[e + 7];
    float v0 = bf2f((unsigned short)T[(size_t)j0 * 64 + lane]);
    float v1 = bf2f((unsigned short)T[(size_t)j1 * 64 + lane]);
    float v2 = bf2f((unsigned short)T[(size_t)j2 * 64 + lane]);
    float v3 = bf2f((unsigned short)T[(size_t)j3 * 64 + lane]);
    float v4 = bf2f((unsigned short)T[(size_t)j4 * 64 + lane]);
    float v5 = bf2f((unsigned short)T[(size_t)j5 * 64 + lane]);
    float v6 = bf2f((unsigned short)T[(size_t)j6 * 64 + lane]);
    float v7 = bf2f((unsigned short)T[(size_t)j7 * 64 + lane]);
    acc += ((v0 + v1) + (v2 + v3)) + ((v4 + v5) + (v6 + v7));
  }
  for (; e + 4 <= e1; e += 4) {
    int j0 = csr[e], j1 = csr[e + 1], j2 = csr[e + 2], j3 = csr[e + 3];
    float v0 = bf2f((unsigned short)T[(size_t)j0 * 64 + lane]);
    float v1 = bf2f((unsigned short)T[(size_t)j1 * 64 + lane]);
    float v2 = bf2f((unsigned short)T[(size_t)j2 * 64 + lane]);
    float v3 = bf2f((unsigned short)T[(size_t)j3 * 64 + lane]);
    acc += (v0 + v1) + (v2 + v3);
  }
  for (; e < e1; e++) acc += bf2f((unsigned short)T[(size_t)csr[e] * 64 + lane]);
  float v = di * acc;
  if (BR) {
    v += bias[lane];
    v = (v >= 0.f) ? v : 0.01f * v;
  }
  if (OSCL) v *= di;
  Out[(size_t)wid * 64 + lane] = (short)f2bf(v);
}

// layer-4 tail fused: hn = LN( leaky(di*sum(t4b) + b4) + resid )   (t4b bf16)
__global__ __launch_bounds__(256) void agg64_ln_k(const short* __restrict__ T, const float* __restrict__ dis,
                                                  const int* __restrict__ off, const int* __restrict__ csr,
                                                  const float* __restrict__ bias, const float* __restrict__ resid,
                                                  const float* __restrict__ g, const float* __restrict__ b,
                                                  float* __restrict__ outh, int n) {
  int wid = (blockIdx.x * 256 + threadIdx.x) >> 6;
  int lane = threadIdx.x & 63;
  if (wid >= n) return;
  float di = dis[wid];
  int e0 = off[wid], e1 = off[wid + 1];
  float acc = bf2f((unsigned short)T[(size_t)wid * 64 + lane]);
  int e = e0;
  for (; e + 8 <= e1; e += 8) {
    int j0 = csr[e], j1 = csr[e + 1], j2 = csr[e + 2], j3 = csr[e + 3];
    int j4 = csr[e + 4], j5 = csr[e + 5], j6 = csr[e + 6], j7 = csr[e + 7];
    float v0 = bf2f((unsigned short)T[(size_t)j0 * 64 + lane]);
    float v1 = bf2f((unsigned short)T[(size_t)j1 * 64 + lane]);
    float v2 = bf2f((unsigned short)T[(size_t)j2 * 64 + lane]);
    float v3 = bf2f((unsigned short)T[(size_t)j3 * 64 + lane]);
    float v4 = bf2f((unsigned short)T[(size_t)j4 * 64 + lane]);
    float v5 = bf2f((unsigned short)T[(size_t)j5 * 64 + lane]);
    float v6 = bf2f((unsigned short)T[(size_t)j6 * 64 + lane]);
    float v7 = bf2f((unsigned short)T[(size_t)j7 * 64 + lane]);
    acc += ((v0 + v1) + (v2 + v3)) + ((v4 + v5) + (v6 + v7));
  }
  for (; e + 4 <= e1; e += 4) {
    int j0 = csr[e], j1 = csr[e + 1], j2 = csr[e + 2], j3 = csr[e + 3];
    float v0 = bf2f((unsigned short)T[(size_t)j0 * 64 + lane]);
    float v1 = bf2f((unsigned short)T[(size_t)j1 * 64 + lane]);
    float v2 = bf2f((unsigned short)T[(size_t)j2 * 64 + lane]);
    float v3 = bf2f((unsigned short)T[(size_t)j3 * 64 + lane]);
    acc += (v0 + v1) + (v2 + v3);
  }
  for (; e < e1; e++) acc += bf2f((unsigned short)T[(size_t)csr[e] * 64 + lane]);
  float v = di * acc + bias[lane];
  v = (v >= 0.f) ? v : 0.01f * v;
  v += resid[(size_t)wid * 64 + lane];
  float s = v, ss = v * v;
#pragma unroll
  for (int o = 32; o > 0; o >>= 1) {
    s += __shfl_xor(s, o);
    ss += __shfl_xor(ss, o);
  }
  float m = s * (1.f / 64.f);
  float var = ss * (1.f / 64.f) - m * m;
  float y = (v - m) * rsqrtf(var + 1e-5f) * g[lane] + b[lane];
  outh[(size_t)wid * 64 + lane] = y;
}

// bf16 gather for the 256-dim layer: z3 = di*(sum + self)
__global__ __launch_bounds__(256) void agg256b_k(const short* __restrict__ T, const float* __restrict__ dis,
                                                 const int* __restrict__ off, const int* __restrict__ csr,
                                                 short* __restrict__ Out, int n) {
  int wid = (blockIdx.x * 256 + threadIdx.x) >> 6;
  int lane = threadIdx.x & 63;
  if (wid >= n) return;
  float di = dis[wid];
  int e0 = off[wid], e1 = off[wid + 1];
  bf16x4 sf = *(const bf16x4*)&T[(size_t)wid * 256 + lane * 4];
  float a0 = bf2f((unsigned short)sf[0]);
  float a1 = bf2f((unsigned short)sf[1]);
  float a2 = bf2f((unsigned short)sf[2]);
  float a3 = bf2f((unsigned short)sf[3]);
  int e = e0;
  for (; e + 8 <= e1; e += 8) {
    bf16x4 t[8];
#pragma unroll
    for (int q = 0; q < 8; q++) t[q] = *(const bf16x4*)&T[(size_t)csr[e + q] * 256 + lane * 4];
#pragma unroll
    for (int q = 0; q < 8; q++) {
      a0 += bf2f((unsigned short)t[q][0]);
      a1 += bf2f((unsigned short)t[q][1]);
      a2 += bf2f((unsigned short)t[q][2]);
      a3 += bf2f((unsigned short)t[q][3]);
    }
  }
  for (; e + 4 <= e1; e += 4) {
    bf16x4 t[4];
#pragma unroll
    for (int q = 0; q < 4; q++) t[q] = *(const bf16x4*)&T[(size_t)csr[e + q] * 256 + lane * 4];
#pragma unroll
    for (int q = 0; q < 4; q++) {
      a0 += bf2f((unsigned short)t[q][0]);
      a1 += bf2f((unsigned short)t[q][1]);
      a2 += bf2f((unsigned short)t[q][2]);
      a3 += bf2f((unsigned short)t[q][3]);
    }
  }
  for (; e < e1; e++) {
    bf16x4 t = *(const bf16x4*)&T[(size_t)csr[e] * 256 + lane * 4];
    a0 += bf2f((unsigned short)t[0]);
    a1 += bf2f((unsigned short)t[1]);
    a2 += bf2f((unsigned short)t[2]);
    a3 += bf2f((unsigned short)t[3]);
  }
  bf16x4 o;
  o[0] = (short)f2bf(di * a0);
  o[1] = (short)f2bf(di * a1);
  o[2] = (short)f2bf(di * a2);
  o[3] = (short)f2bf(di * a3);
  *(bf16x4*)&Out[(size_t)wid * 256 + lane * 4] = o;
}

// ---------------- per-graph max pool + final MLP (fused, one block per graph) ----------------

__global__ __launch_bounds__(256) void pool_mlp_k(const float* __restrict__ hn,
                                                  const float* __restrict__ fc1W, const float* __restrict__ fc1b,
                                                  const float* __restrict__ fng, const float* __restrict__ fnb,
                                                  const float* __restrict__ fc2W, const float* __restrict__ fc2b,
                                                  float* __restrict__ out, int n) {
  const int G = 64;
  int g = blockIdx.x;
  int f = threadIdx.x & 63, c = threadIdx.x >> 6;
  long long s0 = ((long long)g * n + G - 1) / G;
  long long e0 = ((long long)(g + 1) * n + G - 1) / G;
  float m = -INFINITY;
  for (long long i = s0 + c; i < e0; i += 4) m = fmaxf(m, hn[(size_t)i * 64 + f]);
  __shared__ float red[4][64];
  __shared__ float ps[64], qs[64];
  red[c][f] = m;
  __syncthreads();
  if (c == 0) ps[f] = fmaxf(fmaxf(red[0][f], red[1][f]), fmaxf(red[2][f], red[3][f]));
  __syncthreads();
  if (threadIdx.x < 64) {
    int lane = threadIdx.x;
    float q = fc1b[lane];
#pragma unroll 8
    for (int k = 0; k < 64; k++) q = fmaf(ps[k], fc1W[k * 64 + lane], q);
    float s = q, ss = q * q;
#pragma unroll
    for (int o = 32; o > 0; o >>= 1) {
      s += __shfl_xor(s, o);
      ss += __shfl_xor(ss, o);
    }
    float mm = s * (1.f / 64.f);
    float var = ss * (1.f / 64.f) - mm * mm;
    float y = (q - mm) * rsqrtf(var + 1e-5f) * fng[lane] + fnb[lane];
    y = (y >= 0.f) ? y : 0.01f * y;
    qs[lane] = y;
    __builtin_amdgcn_wave_barrier();
    if (lane < 16) {
      float o = fc2b[lane];
#pragma unroll 8
      for (int k = 0; k < 64; k++) o = fmaf(qs[k], fc2W[k * 16 + lane], o);
      out[g * 16 + lane] = o;
    }
  }
}

// ---------------- launch ----------------

extern "C" void kernel_launch(void* const* d_in, const int* in_sizes, int n_in,
                              void* d_out, int out_size, void* d_ws, size_t ws_size,
                              hipStream_t stream) {
  const float* x   = (const float*)d_in[0];
  const int*   ei  = (const int*)d_in[1];
  const float* W1  = (const float*)d_in[3];
  const float* b1  = (const float*)d_in[4];
  const float* W2  = (const float*)d_in[5];
  const float* b2  = (const float*)d_in[6];
  const float* W3  = (const float*)d_in[7];
  const float* b3  = (const float*)d_in[8];
  const float* W4  = (const float*)d_in[9];
  const float* b4  = (const float*)d_in[10];
  const float* Wr  = (const float*)d_in[11];
  const float* br  = (const float*)d_in[12];
  const float* lng = (const float*)d_in[13];
  const float* lnb = (const float*)d_in[14];
  const float* f1W = (const float*)d_in[15];
  const float* f1b = (const float*)d_in[16];
  const float* fng = (const float*)d_in[17];
  const float* fnb = (const float*)d_in[18];
  const float* f2W = (const float*)d_in[19];
  const float* f2b = (const float*)d_in[20];

  int n = in_sizes[0] / 128;   // 50000
  int e = in_sizes[1] / 2;     // 400000
  const int* src = ei;
  const int* dst = ei + e;

  float* arena = (float*)d_ws;
  float* resid = arena;
  short* h2b   = (short*)(arena + (size_t)64 * n);
  short* t4b   = (short*)(arena + (size_t)64 * n);   // n x 64 bf16; h2b dead when written
  short* z3b   = (short*)(arena + (size_t)192 * n);
  float* hn    = arena + (size_t)192 * n;
  short* t1b   = (short*)(arena + (size_t)320 * n);
  short* h1b   = (short*)(arena + (size_t)352 * n);
  short* z2b   = (short*)(arena + (size_t)384 * n);
  float* dis   = arena + (size_t)448 * n;  // n
  int* cnt    = (int*)(dis + n);           // n
  int* off    = cnt + n;                   // n+1
  int* cursor = off + n + 1;               // n
  int* csr    = cursor + n;                // e
  int* bsum   = csr + e;                   // 256
  int* bpre   = bsum + 256;                // 256
  float* pool = (float*)(bpre + 256);      // layout keep
  size_t wq = (((size_t)(pool + 4096)) + 15) & ~(size_t)15;
  short* wc1 = (short*)wq;                 // 64 x 128   (wc1||wcR = fused 128 x 128)
  short* wcR = wc1 + 8192;                 // 64 x 128
  short* wc2 = wcR + 8192;                 // 256 x 64
  short* wc3 = wc2 + 16384;                // 512 x 256
  short* wc4 = wc3 + 131072;               // 64 x 512
  size_t need = ((char*)(wc4 + 32768) - (char*)d_ws) + 64;
  if (ws_size < need) return;

  int nb_n = (n + 255) / 256;     // 196
  int nb_e = (e + 255) / 256;
  int nb_w = (n + 3) / 4;         // one wave per node
  int g_wide = (n + 63) / 64;     // 782
  int g_fused = (n + 127) / 128;  // 391

  // weights -> bf16 [N][K]
  wconv_k<<<960, 256, 0, stream>>>(W1, Wr, W2, W3, W4, wc1, wcR, wc2, wc3, wc4);

  // degree + CSR (hierarchical scan; dis fused into scan_c)
  hipMemsetAsync(cnt, 0, (size_t)n * sizeof(int), stream);
  count_k<<<nb_e, 256, 0, stream>>>(dst, cnt, e);
  scan_a<<<nb_n, 256, 0, stream>>>(cnt, bsum, n);
  scan_b<<<1, 256, 0, stream>>>(bsum, bpre, off + n, nb_n);
  scan_c<<<nb_n, 256, 0, stream>>>(cnt, bpre, off, cursor, dis, n);
  scatter_k<<<nb_e, 256, 0, stream>>>(src, dst, cursor, csr, e);

  // fused L1 + residual: t1b = bf16(dis*(x@W1)); resid = x@Wr + br
  mgemm<128, 128, 2, 2, 1, 0, 0, 0, 1, 1, 4><<<dim3(g_fused, 1), 256, 0, stream>>>(x, wc1, br, t1b, resid, dis, n);
  // h1b = bf16( dis * leaky(di*sum(t1) + b1) )
  aggb64_k<1, 1><<<nb_w, 256, 0, stream>>>(t1b, dis, off, csr, b1, h1b, n);
  // z2b = bf16( di * sum(h1) )
  aggb64_k<0, 0><<<nb_w, 256, 0, stream>>>(h1b, dis, off, csr, nullptr, z2b, n);
  // h2b = bf16( dis * leaky(z2@W2 + b2) )
  mgemm<64, 256, 1, 4, 1, 1, 1, 1, 0, 1, 5><<<dim3(g_wide, 1), 256, 0, stream>>>(z2b, wc2, b2, h2b, nullptr, dis, n);
  // z3b = bf16( di * sum(h2b) )
  agg256b_k<<<nb_w, 256, 0, stream>>>(h2b, dis, off, csr, z3b, n);
  // t4b = bf16( dis * (leaky(z3@W3+b3) @ W4) )   (h3 on-chip, barrier-free)
  fused34_k<<<g_fused, 256, 0, stream>>>(z3b, wc3, b3, wc4, dis, t4b, n);
  // hn = LN( leaky(di*sum(t4b) + b4) + resid )
  agg64_ln_k<<<nb_w, 256, 0, stream>>>(t4b, dis, off, csr, b4, resid, lng, lnb, hn, n);
  // pool + MLP fused
  pool_mlp_k<<<64, 256, 0, stream>>>(hn, f1W, f1b, fng, fnb, f2W, f2b, (float*)d_out, n);
}

// Round 17
// 360.960 us; speedup vs baseline: 1.1537x; 1.1537x over previous
//
#include <hip/hip_runtime.h>
#include <hip/hip_bf16.h>
#include <math.h>

typedef short bf16x8 __attribute__((ext_vector_type(8)));
typedef short bf16x4 __attribute__((ext_vector_type(4)));
typedef float f32x4 __attribute__((ext_vector_type(4)));

__device__ inline unsigned short f2bf(float f) {
  unsigned u = __float_as_uint(f);
  u += 0x7FFF + ((u >> 16) & 1);           // RNE
  return (unsigned short)(u >> 16);
}
__device__ inline float bf2f(unsigned short h) {
  return __uint_as_float(((unsigned)h) << 16);
}
__device__ inline float bflo(unsigned u) { return __uint_as_float(u << 16); }
__device__ inline float bfhi(unsigned u) { return __uint_as_float(u & 0xffff0000u); }

// ---------------- CSR build ----------------

__global__ __launch_bounds__(256) void count_k(const int* __restrict__ dst, int* __restrict__ cnt, int e) {
  int i = blockIdx.x * 256 + threadIdx.x;
  if (i < e) atomicAdd(&cnt[dst[i]], 1);
}

__global__ __launch_bounds__(256) void scan_a(const int* __restrict__ cnt, int* __restrict__ bsum, int n) {
  int i = blockIdx.x * 256 + threadIdx.x;
  int v = (i < n) ? cnt[i] : 0;
#pragma unroll
  for (int o = 32; o > 0; o >>= 1) v += __shfl_xor(v, o);
  __shared__ int ws[4];
  if ((threadIdx.x & 63) == 0) ws[threadIdx.x >> 6] = v;
  __syncthreads();
  if (threadIdx.x == 0) bsum[blockIdx.x] = ws[0] + ws[1] + ws[2] + ws[3];
}

__global__ __launch_bounds__(256) void scan_b(const int* __restrict__ bsum, int* __restrict__ bpre,
                                              int* __restrict__ off_n, int nb) {
  __shared__ int s[256];
  int t = threadIdx.x;
  int v = (t < nb) ? bsum[t] : 0;
  s[t] = v;
  __syncthreads();
  for (int o = 1; o < 256; o <<= 1) {
    int u = (t >= o) ? s[t - o] : 0;
    __syncthreads();
    s[t] += u;
    __syncthreads();
  }
  if (t < nb) bpre[t] = s[t] - v;
  if (t == 255) off_n[0] = s[255];
}

// scan_c also computes dis = rsqrt(cnt+1)
__global__ __launch_bounds__(256) void scan_c(const int* __restrict__ cnt, const int* __restrict__ bpre,
                                              int* __restrict__ off, int* __restrict__ cursor,
                                              float* __restrict__ dis, int n) {
  __shared__ int s[256];
  int i = blockIdx.x * 256 + threadIdx.x;
  int t = threadIdx.x;
  int v = (i < n) ? cnt[i] : 0;
  s[t] = v;
  __syncthreads();
  for (int o = 1; o < 256; o <<= 1) {
    int u = (t >= o) ? s[t - o] : 0;
    __syncthreads();
    s[t] += u;
    __syncthreads();
  }
  if (i < n) {
    int ov = bpre[blockIdx.x] + s[t] - v;
    off[i] = ov;
    cursor[i] = ov;
    dis[i] = rsqrtf((float)v + 1.0f);
  }
}

__global__ __launch_bounds__(256) void scatter_k(const int* __restrict__ src, const int* __restrict__ dst,
                                                 int* __restrict__ cursor, int* __restrict__ csr, int e) {
  int i = blockIdx.x * 256 + threadIdx.x;
  if (i < e) {
    int p = atomicAdd(&cursor[dst[i]], 1);
    csr[p] = src[i];
  }
}

// ------- weight convert: W[K][N] fp32 -> Wc[N][K] bf16 -------

__global__ __launch_bounds__(256) void wconv_k(const float* __restrict__ W1, const float* __restrict__ Wr,
                                               const float* __restrict__ W2, const float* __restrict__ W3,
                                               const float* __restrict__ W4,
                                               short* __restrict__ o1, short* __restrict__ oR,
                                               short* __restrict__ o2, short* __restrict__ o3,
                                               short* __restrict__ o4) {
  int b = blockIdx.x;  // 960 rows total
  const float* W; short* O; int K, N, nr;
  if (b < 64)       { W = W1; O = o1; K = 128; N = 64;  nr = b; }
  else if (b < 128) { W = Wr; O = oR; K = 128; N = 64;  nr = b - 64; }
  else if (b < 384) { W = W2; O = o2; K = 64;  N = 256; nr = b - 128; }
  else if (b < 896) { W = W3; O = o3; K = 256; N = 512; nr = b - 384; }
  else              { W = W4; O = o4; K = 512; N = 64;  nr = b - 896; }
  for (int k = threadIdx.x; k < K; k += 256)
    O[(size_t)nr * K + k] = (short)f2bf(W[(size_t)k * N + nr]);
}

// ------- MFMA GEMM (generic): C[M,NTOT] = A[M,KT] @ Wc[NTOT,KT](bf16) -------

template<int KT, int NTOT, int WM, int WN, int BIAS, int RELU, int ABF, int OBF, int SPLIT, int SCL, int BLK>
__global__ __launch_bounds__(256, BLK) void mgemm(const void* __restrict__ Av,
                                                  const short* __restrict__ Wc,
                                                  const float* __restrict__ bias,
                                                  void* __restrict__ Cv, void* __restrict__ Cv2,
                                                  const float* __restrict__ scl, int M) {
  __shared__ short As[64 * WM][ABF ? 40 : 72];
  __shared__ short Bs[64 * WN][40];
  const int tid = threadIdx.x;
  const int row0 = blockIdx.x * (64 * WM);
  const int col0 = blockIdx.y * (64 * WN);
  const int w = tid >> 6, lane = tid & 63;
  const int wm = w / WN, wn = w % WN;
  const int rm = wm * 64, cn = wn * 64;
  const int lm = lane & 15, lk = (lane >> 4) * 8;

  f32x4 acc[4][4];
#pragma unroll
  for (int i = 0; i < 4; i++)
#pragma unroll
    for (int j = 0; j < 4; j++)
#pragma unroll
      for (int r = 0; r < 4; r++) acc[i][j][r] = 0.f;

  for (int k0 = 0; k0 < KT; k0 += 32) {
#pragma unroll
    for (int p = 0; p < WM; p++) {
      int r = (tid >> 2) + p * 64;
      int kseg = (tid & 3) * 8;
      int gr = row0 + r;
      if (ABF) {
        bf16x8 v = {0, 0, 0, 0, 0, 0, 0, 0};
        if (gr < M) v = *(const bf16x8*)((const short*)Av + (size_t)gr * KT + k0 + kseg);
        *(bf16x8*)&As[r][kseg] = v;
      } else {
        float4 v0 = {0.f, 0.f, 0.f, 0.f}, v1 = {0.f, 0.f, 0.f, 0.f};
        if (gr < M) {
          const float* ap = (const float*)Av + (size_t)gr * KT + k0 + kseg;
          v0 = *(const float4*)ap;
          v1 = *(const float4*)(ap + 4);
        }
        float vv[8] = {v0.x, v0.y, v0.z, v0.w, v1.x, v1.y, v1.z, v1.w};
        bf16x8 hv, lv;
#pragma unroll
        for (int j = 0; j < 8; j++) {
          unsigned short h = f2bf(vv[j]);
          hv[j] = (short)h;
          lv[j] = (short)f2bf(vv[j] - bf2f(h));
        }
        *(bf16x8*)&As[r][kseg] = hv;
        *(bf16x8*)&As[r][32 + kseg] = lv;
      }
    }
#pragma unroll
    for (int p = 0; p < WN; p++) {
      int nr = (tid >> 2) + p * 64;
      int seg = (tid & 3) * 8;
      *(bf16x8*)&Bs[nr][seg] = *(const bf16x8*)(Wc + (size_t)(col0 + nr) * KT + k0 + seg);
    }
    __syncthreads();

    bf16x8 ah[4], al[4], bb[4];
#pragma unroll
    for (int mt = 0; mt < 4; mt++) {
      ah[mt] = *(const bf16x8*)&As[rm + mt * 16 + lm][lk];
      if (!ABF) al[mt] = *(const bf16x8*)&As[rm + mt * 16 + lm][32 + lk];
    }
#pragma unroll
    for (int nt = 0; nt < 4; nt++) bb[nt] = *(const bf16x8*)&Bs[cn + nt * 16 + lm][lk];
#pragma unroll
    for (int mt = 0; mt < 4; mt++)
#pragma unroll
      for (int nt = 0; nt < 4; nt++) {
        acc[mt][nt] = __builtin_amdgcn_mfma_f32_16x16x32_bf16(ah[mt], bb[nt], acc[mt][nt], 0, 0, 0);
        if (!ABF)
          acc[mt][nt] = __builtin_amdgcn_mfma_f32_16x16x32_bf16(al[mt], bb[nt], acc[mt][nt], 0, 0, 0);
      }
    __syncthreads();
  }

  if (SPLIT) {
    short* epi = (short*)&As[0][0];   // 128*64 shorts = 16 KB
    if (wn == 0) {
#pragma unroll
      for (int mt = 0; mt < 4; mt++) {
        int lr = rm + mt * 16 + (lane >> 4) * 4;
#pragma unroll
        for (int r = 0; r < 4; r++) {
          int gr = row0 + lr + r;
          float sc = (SCL && gr < M) ? scl[gr] : 0.f;
#pragma unroll
          for (int nt = 0; nt < 4; nt++)
            epi[(lr + r) * 64 + nt * 16 + lm] = (short)f2bf(acc[mt][nt][r] * sc);
        }
      }
    } else {
#pragma unroll
      for (int mt = 0; mt < 4; mt++) {
        int grb = row0 + rm + mt * 16 + (lane >> 4) * 4;
#pragma unroll
        for (int nt = 0; nt < 4; nt++) {
          int gc = nt * 16 + lm;
          float bv = bias[gc];
#pragma unroll
          for (int r = 0; r < 4; r++) {
            int gr = grb + r;
            if (gr < M) ((float*)Cv2)[(size_t)gr * 64 + gc] = acc[mt][nt][r] + bv;
          }
        }
      }
    }
    __syncthreads();
    int base = tid * 32;
    int row = base >> 6, col = base & 63;
    int gr = row0 + row;
    if (gr < M) {
#pragma unroll
      for (int q = 0; q < 4; q++)
        *(bf16x8*)((short*)Cv + (size_t)gr * 64 + col + q * 8) = *(bf16x8*)&epi[base + q * 8];
    }
  } else if (OBF && WM == 1) {
    short* epi = &Bs[0][0];
    const int NCOL = 64 * WN;
    float bvv[4];
#pragma unroll
    for (int nt = 0; nt < 4; nt++) bvv[nt] = BIAS ? bias[col0 + cn + nt * 16 + lm] : 0.f;
#pragma unroll
    for (int mt = 0; mt < 4; mt++) {
      __syncthreads();
#pragma unroll
      for (int r = 0; r < 4; r++) {
        int gr = row0 + mt * 16 + (lane >> 4) * 4 + r;
        float sc = (SCL && gr < M) ? scl[gr] : 1.f;
#pragma unroll
        for (int nt = 0; nt < 4; nt++) {
          float v = acc[mt][nt][r] + bvv[nt];
          if (RELU) v = (v >= 0.f) ? v : 0.01f * v;
          if (SCL) v *= sc;
          epi[((lane >> 4) * 4 + r) * NCOL + cn + nt * 16 + lm] = (short)f2bf(v);
        }
      }
      __syncthreads();
      const int per = (16 * NCOL) / 256;
      int base = tid * per;
      int lr = base / NCOL, lc = base % NCOL;
      int gr = row0 + mt * 16 + lr;
      if (gr < M) {
#pragma unroll
        for (int q = 0; q < per / 8; q++)
          *(bf16x8*)((short*)Cv + (size_t)gr * NTOT + col0 + lc + q * 8) = *(bf16x8*)&epi[base + q * 8];
      }
    }
  } else {
#pragma unroll
    for (int mt = 0; mt < 4; mt++) {
      int grb = row0 + rm + mt * 16 + (lane >> 4) * 4;
#pragma unroll
      for (int nt = 0; nt < 4; nt++) {
        int gc = col0 + cn + nt * 16 + lm;
        float bv = BIAS ? bias[gc] : 0.f;
#pragma unroll
        for (int r = 0; r < 4; r++) {
          int gr = grb + r;
          if (gr < M) {
            float v = acc[mt][nt][r] + bv;
            if (RELU) v = (v >= 0.f) ? v : 0.01f * v;
            if (SCL) v *= scl[gr];
            if (OBF) ((short*)Cv)[(size_t)gr * NTOT + gc] = (short)f2bf(v);
            else     ((float*)Cv)[(size_t)gr * NTOT + gc] = v;
          }
        }
      }
    }
  }
}

// ------- fused layer3+layer4 (R15 structure, reverted): ping-pong LDS, bf16 out -------

__global__ __launch_bounds__(256, 3) void fused34_k(const short* __restrict__ z3,
                                                    const short* __restrict__ W3c,  // [512][256] bf16
                                                    const float* __restrict__ b3,
                                                    const short* __restrict__ W4c,  // [64][512] bf16
                                                    const float* __restrict__ dis,
                                                    short* __restrict__ T4, int M) {
  __shared__ short Bs[2][32][264];  // W3 chunk ping-pong
  __shared__ short Ws4[2][64][40];  // W4 chunk ping-pong
  __shared__ short Hs[64][40];      // h3 chunk, A-layout (wave-private rows)
  const int tid = threadIdx.x;
  const int row0 = blockIdx.x * 64;
  const int w = tid >> 6, lane = tid & 63;
  const int lm = lane & 15, lk = (lane >> 4) * 8;
  const int rquad = (lane >> 4) * 4;
  const int w4row = tid >> 2, w4seg = (tid & 3) * 8;

  bf16x8 afr[8];
  {
    int gr = row0 + w * 16 + lm;
    bool ok = gr < M;
    const short* zp = z3 + (size_t)gr * 256 + lk;
#pragma unroll
    for (int kc = 0; kc < 8; kc++) {
      bf16x8 v = {0, 0, 0, 0, 0, 0, 0, 0};
      if (ok) v = *(const bf16x8*)(zp + kc * 32);
      afr[kc] = v;
    }
  }

  f32x4 t4acc[4];
#pragma unroll
  for (int nt = 0; nt < 4; nt++)
#pragma unroll
    for (int r = 0; r < 4; r++) t4acc[nt][r] = 0.f;

  bf16x8 pw3[4];
  bf16x8 pw4;
#pragma unroll
  for (int q = 0; q < 4; q++) {
    int flat = q * 2048 + tid * 8;
    pw3[q] = *(const bf16x8*)(W3c + flat);
  }
  pw4 = *(const bf16x8*)(W4c + (size_t)w4row * 512 + w4seg);
#pragma unroll
  for (int q = 0; q < 4; q++) {
    int flat = q * 2048 + tid * 8;
    *(bf16x8*)&Bs[0][flat >> 8][flat & 255] = pw3[q];
  }
  *(bf16x8*)&Ws4[0][w4row][w4seg] = pw4;
  __syncthreads();

  for (int c = 0; c < 16; c++) {
    int cur = c & 1, nxt = cur ^ 1;
    if (c < 15) {
#pragma unroll
      for (int q = 0; q < 4; q++) {
        int flat = q * 2048 + tid * 8;
        pw3[q] = *(const bf16x8*)(W3c + (size_t)(c + 1) * 32 * 256 + flat);
      }
      pw4 = *(const bf16x8*)(W4c + (size_t)w4row * 512 + (c + 1) * 32 + w4seg);
    }

    f32x4 acc1[2];
#pragma unroll
    for (int nt = 0; nt < 2; nt++)
#pragma unroll
      for (int r = 0; r < 4; r++) acc1[nt][r] = 0.f;
#pragma unroll
    for (int k0 = 0; k0 < 8; k0++) {
      bf16x8 bb[2];
#pragma unroll
      for (int nt = 0; nt < 2; nt++) bb[nt] = *(const bf16x8*)&Bs[cur][nt * 16 + lm][k0 * 32 + lk];
#pragma unroll
      for (int nt = 0; nt < 2; nt++)
        acc1[nt] = __builtin_amdgcn_mfma_f32_16x16x32_bf16(afr[k0], bb[nt], acc1[nt], 0, 0, 0);
    }
#pragma unroll
    for (int nt = 0; nt < 2; nt++) {
      float bv = b3[c * 32 + nt * 16 + lm];
#pragma unroll
      for (int r = 0; r < 4; r++) {
        float v = acc1[nt][r] + bv;
        v = (v >= 0.f) ? v : 0.01f * v;
        Hs[w * 16 + rquad + r][nt * 16 + lm] = (short)f2bf(v);
      }
    }
    {
      bf16x8 ah2 = *(const bf16x8*)&Hs[w * 16 + lm][lk];
      bf16x8 bb2[4];
#pragma unroll
      for (int nt = 0; nt < 4; nt++) bb2[nt] = *(const bf16x8*)&Ws4[cur][nt * 16 + lm][lk];
#pragma unroll
      for (int nt = 0; nt < 4; nt++)
        t4acc[nt] = __builtin_amdgcn_mfma_f32_16x16x32_bf16(ah2, bb2[nt], t4acc[nt], 0, 0, 0);
    }
    if (c < 15) {
#pragma unroll
      for (int q = 0; q < 4; q++) {
        int flat = q * 2048 + tid * 8;
        *(bf16x8*)&Bs[nxt][flat >> 8][flat & 255] = pw3[q];
      }
      *(bf16x8*)&Ws4[nxt][w4row][w4seg] = pw4;
    }
    __syncthreads();
  }
  // epilogue: bf16 t4 = acc*dis, staged through Bs (dead) for full-line writes
  short* epi = (short*)&Bs[0][0][0];   // 64*64 shorts = 8 KB
#pragma unroll
  for (int r = 0; r < 4; r++) {
    int lr = w * 16 + rquad + r;
    int gr = row0 + lr;
    float sc = (gr < M) ? dis[gr] : 0.f;
#pragma unroll
    for (int nt = 0; nt < 4; nt++)
      epi[lr * 64 + nt * 16 + lm] = (short)f2bf(t4acc[nt][r] * sc);
  }
  __syncthreads();
  {
    int base = tid * 16;               // 4096 shorts / 256 threads
    int row = base >> 6, col = base & 63;
    int gr = row0 + row;
    if (gr < M) {
      *(bf16x8*)(T4 + (size_t)gr * 64 + col)     = *(bf16x8*)&epi[base];
      *(bf16x8*)(T4 + (size_t)gr * 64 + col + 8) = *(bf16x8*)&epi[base + 8];
    }
  }
}

// ------- Aggregation (dis-free; rows pre-scaled). Half-wave: 2 nodes/wave. -------
// Lanes 0..31 -> node 2w, lanes 32..63 -> node 2w+1; each lane covers 2 features (4B).

template<int BR, int OSCL>
__global__ __launch_bounds__(256) void aggb64_k(const short* __restrict__ T, const float* __restrict__ dis,
                                                const int* __restrict__ off, const int* __restrict__ csr,
                                                const float* __restrict__ bias, short* __restrict__ Out, int n) {
  int wv = (blockIdx.x * 256 + threadIdx.x) >> 6;
  int lane = threadIdx.x & 63;
  int half = lane >> 5, hl = lane & 31;
  int wid = wv * 2 + half;
  if (wid >= n) return;
  float di = dis[wid];
  int e0 = off[wid], e1 = off[wid + 1];
  const unsigned* Tw = (const unsigned*)T;   // 2 bf16 per unsigned
  unsigned su = Tw[(size_t)wid * 32 + hl];
  float a0 = bflo(su), a1 = bfhi(su);
  int e = e0;
  for (; e + 8 <= e1; e += 8) {
    int j0 = csr[e], j1 = csr[e + 1], j2 = csr[e + 2], j3 = csr[e + 3];
    int j4 = csr[e + 4], j5 = csr[e + 5], j6 = csr[e + 6], j7 = csr[e + 7];
    unsigned u0 = Tw[(size_t)j0 * 32 + hl];
    unsigned u1 = Tw[(size_t)j1 * 32 + hl];
    unsigned u2 = Tw[(size_t)j2 * 32 + hl];
    unsigned u3 = Tw[(size_t)j3 * 32 + hl];
    unsigned u4 = Tw[(size_t)j4 * 32 + hl];
    unsigned u5 = Tw[(size_t)j5 * 32 + hl];
    unsigned u6 = Tw[(size_t)j6 * 32 + hl];
    unsigned u7 = Tw[(size_t)j7 * 32 + hl];
    a0 += ((bflo(u0) + bflo(u1)) + (bflo(u2) + bflo(u3))) + ((bflo(u4) + bflo(u5)) + (bflo(u6) + bflo(u7)));
    a1 += ((bfhi(u0) + bfhi(u1)) + (bfhi(u2) + bfhi(u3))) + ((bfhi(u4) + bfhi(u5)) + (bfhi(u6) + bfhi(u7)));
  }
  for (; e + 4 <= e1; e += 4) {
    int j0 = csr[e], j1 = csr[e + 1], j2 = csr[e + 2], j3 = csr[e + 3];
    unsigned u0 = Tw[(size_t)j0 * 32 + hl];
    unsigned u1 = Tw[(size_t)j1 * 32 + hl];
    unsigned u2 = Tw[(size_t)j2 * 32 + hl];
    unsigned u3 = Tw[(size_t)j3 * 32 + hl];
    a0 += (bflo(u0) + bflo(u1)) + (bflo(u2) + bflo(u3));
    a1 += (bfhi(u0) + bfhi(u1)) + (bfhi(u2) + bfhi(u3));
  }
  for (; e < e1; e++) {
    unsigned u = Tw[(size_t)csr[e] * 32 + hl];
    a0 += bflo(u);
    a1 += bfhi(u);
  }
  float v0 = di * a0, v1 = di * a1;
  if (BR) {
    v0 += bias[hl * 2];
    v1 += bias[hl * 2 + 1];
    v0 = (v0 >= 0.f) ? v0 : 0.01f * v0;
    v1 = (v1 >= 0.f) ? v1 : 0.01f * v1;
  }
  if (OSCL) { v0 *= di; v1 *= di; }
  unsigned o = (unsigned)f2bf(v0) | ((unsigned)f2bf(v1) << 16);
  ((unsigned*)Out)[(size_t)wid * 32 + hl] = o;
}

// layer-4 tail fused: hn = LN( leaky(di*sum(t4b) + b4) + resid )   (t4b bf16)
__global__ __launch_bounds__(256) void agg64_ln_k(const short* __restrict__ T, const float* __restrict__ dis,
                                                  const int* __restrict__ off, const int* __restrict__ csr,
                                                  const float* __restrict__ bias, const float* __restrict__ resid,
                                                  const float* __restrict__ g, const float* __restrict__ b,
                                                  float* __restrict__ outh, int n) {
  int wid = (blockIdx.x * 256 + threadIdx.x) >> 6;
  int lane = threadIdx.x & 63;
  if (wid >= n) return;
  float di = dis[wid];
  int e0 = off[wid], e1 = off[wid + 1];
  float acc = bf2f((unsigned short)T[(size_t)wid * 64 + lane]);
  int e = e0;
  for (; e + 8 <= e1; e += 8) {
    int j0 = csr[e], j1 = csr[e + 1], j2 = csr[e + 2], j3 = csr[e + 3];
    int j4 = csr[e + 4], j5 = csr[e + 5], j6 = csr[e + 6], j7 = csr[e + 7];
    float v0 = bf2f((unsigned short)T[(size_t)j0 * 64 + lane]);
    float v1 = bf2f((unsigned short)T[(size_t)j1 * 64 + lane]);
    float v2 = bf2f((unsigned short)T[(size_t)j2 * 64 + lane]);
    float v3 = bf2f((unsigned short)T[(size_t)j3 * 64 + lane]);
    float v4 = bf2f((unsigned short)T[(size_t)j4 * 64 + lane]);
    float v5 = bf2f((unsigned short)T[(size_t)j5 * 64 + lane]);
    float v6 = bf2f((unsigned short)T[(size_t)j6 * 64 + lane]);
    float v7 = bf2f((unsigned short)T[(size_t)j7 * 64 + lane]);
    acc += ((v0 + v1) + (v2 + v3)) + ((v4 + v5) + (v6 + v7));
  }
  for (; e + 4 <= e1; e += 4) {
    int j0 = csr[e], j1 = csr[e + 1], j2 = csr[e + 2], j3 = csr[e + 3];
    float v0 = bf2f((unsigned short)T[(size_t)j0 * 64 + lane]);
    float v1 = bf2f((unsigned short)T[(size_t)j1 * 64 + lane]);
    float v2 = bf2f((unsigned short)T[(size_t)j2 * 64 + lane]);
    float v3 = bf2f((unsigned short)T[(size_t)j3 * 64 + lane]);
    acc += (v0 + v1) + (v2 + v3);
  }
  for (; e < e1; e++) acc += bf2f((unsigned short)T[(size_t)csr[e] * 64 + lane]);
  float v = di * acc + bias[lane];
  v = (v >= 0.f) ? v : 0.01f * v;
  v += resid[(size_t)wid * 64 + lane];
  float s = v, ss = v * v;
#pragma unroll
  for (int o = 32; o > 0; o >>= 1) {
    s += __shfl_xor(s, o);
    ss += __shfl_xor(ss, o);
  }
  float m = s * (1.f / 64.f);
  float var = ss * (1.f / 64.f) - m * m;
  float y = (v - m) * rsqrtf(var + 1e-5f) * g[lane] + b[lane];
  outh[(size_t)wid * 64 + lane] = y;
}

// 256-dim bf16 gather, half-wave dual-node: lane covers 8 features (16B)
__global__ __launch_bounds__(256) void agg256b_k(const short* __restrict__ T, const float* __restrict__ dis,
                                                 const int* __restrict__ off, const int* __restrict__ csr,
                                                 short* __restrict__ Out, int n) {
  int wv = (blockIdx.x * 256 + threadIdx.x) >> 6;
  int lane = threadIdx.x & 63;
  int half = lane >> 5, hl = lane & 31;
  int wid = wv * 2 + half;
  if (wid >= n) return;
  float di = dis[wid];
  int e0 = off[wid], e1 = off[wid + 1];
  bf16x8 sf = *(const bf16x8*)&T[(size_t)wid * 256 + hl * 8];
  float a[8];
#pragma unroll
  for (int q = 0; q < 8; q++) a[q] = bf2f((unsigned short)sf[q]);
  int e = e0;
  for (; e + 4 <= e1; e += 4) {
    bf16x8 t0 = *(const bf16x8*)&T[(size_t)csr[e] * 256 + hl * 8];
    bf16x8 t1 = *(const bf16x8*)&T[(size_t)csr[e + 1] * 256 + hl * 8];
    bf16x8 t2 = *(const bf16x8*)&T[(size_t)csr[e + 2] * 256 + hl * 8];
    bf16x8 t3 = *(const bf16x8*)&T[(size_t)csr[e + 3] * 256 + hl * 8];
#pragma unroll
    for (int q = 0; q < 8; q++)
      a[q] += (bf2f((unsigned short)t0[q]) + bf2f((unsigned short)t1[q])) +
              (bf2f((unsigned short)t2[q]) + bf2f((unsigned short)t3[q]));
  }
  for (; e < e1; e++) {
    bf16x8 t = *(const bf16x8*)&T[(size_t)csr[e] * 256 + hl * 8];
#pragma unroll
    for (int q = 0; q < 8; q++) a[q] += bf2f((unsigned short)t[q]);
  }
  bf16x8 o;
#pragma unroll
  for (int q = 0; q < 8; q++) o[q] = (short)f2bf(di * a[q]);
  *(bf16x8*)&Out[(size_t)wid * 256 + hl * 8] = o;
}

// ---------------- per-graph max pool + final MLP (fused, one block per graph) ----------------

__global__ __launch_bounds__(256) void pool_mlp_k(const float* __restrict__ hn,
                                                  const float* __restrict__ fc1W, const float* __restrict__ fc1b,
                                                  const float* __restrict__ fng, const float* __restrict__ fnb,
                                                  const float* __restrict__ fc2W, const float* __restrict__ fc2b,
                                                  float* __restrict__ out, int n) {
  const int G = 64;
  int g = blockIdx.x;
  int f = threadIdx.x & 63, c = threadIdx.x >> 6;
  long long s0 = ((long long)g * n + G - 1) / G;
  long long e0 = ((long long)(g + 1) * n + G - 1) / G;
  float m = -INFINITY;
  for (long long i = s0 + c; i < e0; i += 4) m = fmaxf(m, hn[(size_t)i * 64 + f]);
  __shared__ float red[4][64];
  __shared__ float ps[64], qs[64];
  red[c][f] = m;
  __syncthreads();
  if (c == 0) ps[f] = fmaxf(fmaxf(red[0][f], red[1][f]), fmaxf(red[2][f], red[3][f]));
  __syncthreads();
  if (threadIdx.x < 64) {
    int lane = threadIdx.x;
    float q = fc1b[lane];
#pragma unroll 8
    for (int k = 0; k < 64; k++) q = fmaf(ps[k], fc1W[k * 64 + lane], q);
    float s = q, ss = q * q;
#pragma unroll
    for (int o = 32; o > 0; o >>= 1) {
      s += __shfl_xor(s, o);
      ss += __shfl_xor(ss, o);
    }
    float mm = s * (1.f / 64.f);
    float var = ss * (1.f / 64.f) - mm * mm;
    float y = (q - mm) * rsqrtf(var + 1e-5f) * fng[lane] + fnb[lane];
    y = (y >= 0.f) ? y : 0.01f * y;
    qs[lane] = y;
    __builtin_amdgcn_wave_barrier();
    if (lane < 16) {
      float o = fc2b[lane];
#pragma unroll 8
      for (int k = 0; k < 64; k++) o = fmaf(qs[k], fc2W[k * 16 + lane], o);
      out[g * 16 + lane] = o;
    }
  }
}

// ---------------- launch ----------------

extern "C" void kernel_launch(void* const* d_in, const int* in_sizes, int n_in,
                              void* d_out, int out_size, void* d_ws, size_t ws_size,
                              hipStream_t stream) {
  const float* x   = (const float*)d_in[0];
  const int*   ei  = (const int*)d_in[1];
  const float* W1  = (const float*)d_in[3];
  const float* b1  = (const float*)d_in[4];
  const float* W2  = (const float*)d_in[5];
  const float* b2  = (const float*)d_in[6];
  const float* W3  = (const float*)d_in[7];
  const float* b3  = (const float*)d_in[8];
  const float* W4  = (const float*)d_in[9];
  const float* b4  = (const float*)d_in[10];
  const float* Wr  = (const float*)d_in[11];
  const float* br  = (const float*)d_in[12];
  const float* lng = (const float*)d_in[13];
  const float* lnb = (const float*)d_in[14];
  const float* f1W = (const float*)d_in[15];
  const float* f1b = (const float*)d_in[16];
  const float* fng = (const float*)d_in[17];
  const float* fnb = (const float*)d_in[18];
  const float* f2W = (const float*)d_in[19];
  const float* f2b = (const float*)d_in[20];

  int n = in_sizes[0] / 128;   // 50000
  int e = in_sizes[1] / 2;     // 400000
  const int* src = ei;
  const int* dst = ei + e;

  float* arena = (float*)d_ws;
  float* resid = arena;
  short* h2b   = (short*)(arena + (size_t)64 * n);
  short* t4b   = (short*)(arena + (size_t)64 * n);   // n x 64 bf16; h2b dead when written
  short* z3b   = (short*)(arena + (size_t)192 * n);
  float* hn    = arena + (size_t)192 * n;
  short* t1b   = (short*)(arena + (size_t)320 * n);
  short* h1b   = (short*)(arena + (size_t)352 * n);
  short* z2b   = (short*)(arena + (size_t)384 * n);
  float* dis   = arena + (size_t)448 * n;  // n
  int* cnt    = (int*)(dis + n);           // n
  int* off    = cnt + n;                   // n+1
  int* cursor = off + n + 1;               // n
  int* csr    = cursor + n;                // e
  int* bsum   = csr + e;                   // 256
  int* bpre   = bsum + 256;                // 256
  float* pool = (float*)(bpre + 256);      // layout keep
  size_t wq = (((size_t)(pool + 4096)) + 15) & ~(size_t)15;
  short* wc1 = (short*)wq;                 // 64 x 128   (wc1||wcR = fused 128 x 128)
  short* wcR = wc1 + 8192;                 // 64 x 128
  short* wc2 = wcR + 8192;                 // 256 x 64
  short* wc3 = wc2 + 16384;                // 512 x 256
  short* wc4 = wc3 + 131072;               // 64 x 512
  size_t need = ((char*)(wc4 + 32768) - (char*)d_ws) + 64;
  if (ws_size < need) return;

  int nb_n = (n + 255) / 256;       // 196
  int nb_e = (e + 255) / 256;
  int nb_w = (n + 3) / 4;           // one wave per node
  int nb_w2 = ((n + 1) / 2 + 3) / 4; // two nodes per wave
  int g_wide = (n + 63) / 64;       // 782
  int g_fused = (n + 127) / 128;    // 391

  // weights -> bf16 [N][K]
  wconv_k<<<960, 256, 0, stream>>>(W1, Wr, W2, W3, W4, wc1, wcR, wc2, wc3, wc4);

  // degree + CSR (hierarchical scan; dis fused into scan_c)
  hipMemsetAsync(cnt, 0, (size_t)n * sizeof(int), stream);
  count_k<<<nb_e, 256, 0, stream>>>(dst, cnt, e);
  scan_a<<<nb_n, 256, 0, stream>>>(cnt, bsum, n);
  scan_b<<<1, 256, 0, stream>>>(bsum, bpre, off + n, nb_n);
  scan_c<<<nb_n, 256, 0, stream>>>(cnt, bpre, off, cursor, dis, n);
  scatter_k<<<nb_e, 256, 0, stream>>>(src, dst, cursor, csr, e);

  // fused L1 + residual: t1b = bf16(dis*(x@W1)); resid = x@Wr + br
  mgemm<128, 128, 2, 2, 1, 0, 0, 0, 1, 1, 4><<<dim3(g_fused, 1), 256, 0, stream>>>(x, wc1, br, t1b, resid, dis, n);
  // h1b = bf16( dis * leaky(di*sum(t1) + b1) )
  aggb64_k<1, 1><<<nb_w2, 256, 0, stream>>>(t1b, dis, off, csr, b1, h1b, n);
  // z2b = bf16( di * sum(h1) )
  aggb64_k<0, 0><<<nb_w2, 256, 0, stream>>>(h1b, dis, off, csr, nullptr, z2b, n);
  // h2b = bf16( dis * leaky(z2@W2 + b2) )
  mgemm<64, 256, 1, 4, 1, 1, 1, 1, 0, 1, 5><<<dim3(g_wide, 1), 256, 0, stream>>>(z2b, wc2, b2, h2b, nullptr, dis, n);
  // z3b = bf16( di * sum(h2b) )
  agg256b_k<<<nb_w2, 256, 0, stream>>>(h2b, dis, off, csr, z3b, n);
  // t4b = bf16( dis * (leaky(z3@W3+b3) @ W4) )   (h3 on-chip, ping-pong)
  fused34_k<<<g_wide, 256, 0, stream>>>(z3b, wc3, b3, wc4, dis, t4b, n);
  // hn = LN( leaky(di*sum(t4b) + b4) + resid )
  agg64_ln_k<<<nb_w, 256, 0, stream>>>(t4b, dis, off, csr, b4, resid, lng, lnb, hn, n);
  // pool + MLP fused
  pool_mlp_k<<<64, 256, 0, stream>>>(hn, f1W, f1b, fng, fnb, f2W, f2b, (float*)d_out, n);
}

// Round 18
// 357.158 us; speedup vs baseline: 1.1660x; 1.0106x over previous
//
#include <hip/hip_runtime.h>
#include <hip/hip_bf16.h>
#include <math.h>

typedef short bf16x8 __attribute__((ext_vector_type(8)));
typedef short bf16x4 __attribute__((ext_vector_type(4)));
typedef float f32x4 __attribute__((ext_vector_type(4)));

__device__ inline unsigned short f2bf(float f) {
  unsigned u = __float_as_uint(f);
  u += 0x7FFF + ((u >> 16) & 1);           // RNE
  return (unsigned short)(u >> 16);
}
__device__ inline float bf2f(unsigned short h) {
  return __uint_as_float(((unsigned)h) << 16);
}
__device__ inline float bflo(unsigned u) { return __uint_as_float(u << 16); }
__device__ inline float bfhi(unsigned u) { return __uint_as_float(u & 0xffff0000u); }

// ---------------- CSR build ----------------

__global__ __launch_bounds__(256) void count_k(const int* __restrict__ dst, int* __restrict__ cnt, int e) {
  int i = blockIdx.x * 256 + threadIdx.x;
  if (i < e) atomicAdd(&cnt[dst[i]], 1);
}

__global__ __launch_bounds__(256) void scan_a(const int* __restrict__ cnt, int* __restrict__ bsum, int n) {
  int i = blockIdx.x * 256 + threadIdx.x;
  int v = (i < n) ? cnt[i] : 0;
#pragma unroll
  for (int o = 32; o > 0; o >>= 1) v += __shfl_xor(v, o);
  __shared__ int ws[4];
  if ((threadIdx.x & 63) == 0) ws[threadIdx.x >> 6] = v;
  __syncthreads();
  if (threadIdx.x == 0) bsum[blockIdx.x] = ws[0] + ws[1] + ws[2] + ws[3];
}

__global__ __launch_bounds__(256) void scan_b(const int* __restrict__ bsum, int* __restrict__ bpre,
                                              int* __restrict__ off_n, int nb) {
  __shared__ int s[256];
  int t = threadIdx.x;
  int v = (t < nb) ? bsum[t] : 0;
  s[t] = v;
  __syncthreads();
  for (int o = 1; o < 256; o <<= 1) {
    int u = (t >= o) ? s[t - o] : 0;
    __syncthreads();
    s[t] += u;
    __syncthreads();
  }
  if (t < nb) bpre[t] = s[t] - v;
  if (t == 255) off_n[0] = s[255];
}

// scan_c also computes dis = rsqrt(cnt+1)
__global__ __launch_bounds__(256) void scan_c(const int* __restrict__ cnt, const int* __restrict__ bpre,
                                              int* __restrict__ off, int* __restrict__ cursor,
                                              float* __restrict__ dis, int n) {
  __shared__ int s[256];
  int i = blockIdx.x * 256 + threadIdx.x;
  int t = threadIdx.x;
  int v = (i < n) ? cnt[i] : 0;
  s[t] = v;
  __syncthreads();
  for (int o = 1; o < 256; o <<= 1) {
    int u = (t >= o) ? s[t - o] : 0;
    __syncthreads();
    s[t] += u;
    __syncthreads();
  }
  if (i < n) {
    int ov = bpre[blockIdx.x] + s[t] - v;
    off[i] = ov;
    cursor[i] = ov;
    dis[i] = rsqrtf((float)v + 1.0f);
  }
}

__global__ __launch_bounds__(256) void scatter_k(const int* __restrict__ src, const int* __restrict__ dst,
                                                 int* __restrict__ cursor, int* __restrict__ csr, int e) {
  int i = blockIdx.x * 256 + threadIdx.x;
  if (i < e) {
    int p = atomicAdd(&cursor[dst[i]], 1);
    csr[p] = src[i];
  }
}

// ------- weight convert: W[K][N] fp32 -> Wc[N][K] bf16 -------

__global__ __launch_bounds__(256) void wconv_k(const float* __restrict__ W1, const float* __restrict__ Wr,
                                               const float* __restrict__ W2, const float* __restrict__ W3,
                                               const float* __restrict__ W4,
                                               short* __restrict__ o1, short* __restrict__ oR,
                                               short* __restrict__ o2, short* __restrict__ o3,
                                               short* __restrict__ o4) {
  int b = blockIdx.x;  // 960 rows total
  const float* W; short* O; int K, N, nr;
  if (b < 64)       { W = W1; O = o1; K = 128; N = 64;  nr = b; }
  else if (b < 128) { W = Wr; O = oR; K = 128; N = 64;  nr = b - 64; }
  else if (b < 384) { W = W2; O = o2; K = 64;  N = 256; nr = b - 128; }
  else if (b < 896) { W = W3; O = o3; K = 256; N = 512; nr = b - 384; }
  else              { W = W4; O = o4; K = 512; N = 64;  nr = b - 896; }
  for (int k = threadIdx.x; k < K; k += 256)
    O[(size_t)nr * K + k] = (short)f2bf(W[(size_t)k * N + nr]);
}

// ------- MFMA GEMM (generic): C[M,NTOT] = A[M,KT] @ Wc[NTOT,KT](bf16) -------

template<int KT, int NTOT, int WM, int WN, int BIAS, int RELU, int ABF, int OBF, int SPLIT, int SCL, int BLK>
__global__ __launch_bounds__(256, BLK) void mgemm(const void* __restrict__ Av,
                                                  const short* __restrict__ Wc,
                                                  const float* __restrict__ bias,
                                                  void* __restrict__ Cv, void* __restrict__ Cv2,
                                                  const float* __restrict__ scl, int M) {
  __shared__ short As[64 * WM][ABF ? 40 : 72];
  __shared__ short Bs[64 * WN][40];
  const int tid = threadIdx.x;
  const int row0 = blockIdx.x * (64 * WM);
  const int col0 = blockIdx.y * (64 * WN);
  const int w = tid >> 6, lane = tid & 63;
  const int wm = w / WN, wn = w % WN;
  const int rm = wm * 64, cn = wn * 64;
  const int lm = lane & 15, lk = (lane >> 4) * 8;

  f32x4 acc[4][4];
#pragma unroll
  for (int i = 0; i < 4; i++)
#pragma unroll
    for (int j = 0; j < 4; j++)
#pragma unroll
      for (int r = 0; r < 4; r++) acc[i][j][r] = 0.f;

  for (int k0 = 0; k0 < KT; k0 += 32) {
#pragma unroll
    for (int p = 0; p < WM; p++) {
      int r = (tid >> 2) + p * 64;
      int kseg = (tid & 3) * 8;
      int gr = row0 + r;
      if (ABF) {
        bf16x8 v = {0, 0, 0, 0, 0, 0, 0, 0};
        if (gr < M) v = *(const bf16x8*)((const short*)Av + (size_t)gr * KT + k0 + kseg);
        *(bf16x8*)&As[r][kseg] = v;
      } else {
        float4 v0 = {0.f, 0.f, 0.f, 0.f}, v1 = {0.f, 0.f, 0.f, 0.f};
        if (gr < M) {
          const float* ap = (const float*)Av + (size_t)gr * KT + k0 + kseg;
          v0 = *(const float4*)ap;
          v1 = *(const float4*)(ap + 4);
        }
        float vv[8] = {v0.x, v0.y, v0.z, v0.w, v1.x, v1.y, v1.z, v1.w};
        bf16x8 hv, lv;
#pragma unroll
        for (int j = 0; j < 8; j++) {
          unsigned short h = f2bf(vv[j]);
          hv[j] = (short)h;
          lv[j] = (short)f2bf(vv[j] - bf2f(h));
        }
        *(bf16x8*)&As[r][kseg] = hv;
        *(bf16x8*)&As[r][32 + kseg] = lv;
      }
    }
#pragma unroll
    for (int p = 0; p < WN; p++) {
      int nr = (tid >> 2) + p * 64;
      int seg = (tid & 3) * 8;
      *(bf16x8*)&Bs[nr][seg] = *(const bf16x8*)(Wc + (size_t)(col0 + nr) * KT + k0 + seg);
    }
    __syncthreads();

    bf16x8 ah[4], al[4], bb[4];
#pragma unroll
    for (int mt = 0; mt < 4; mt++) {
      ah[mt] = *(const bf16x8*)&As[rm + mt * 16 + lm][lk];
      if (!ABF) al[mt] = *(const bf16x8*)&As[rm + mt * 16 + lm][32 + lk];
    }
#pragma unroll
    for (int nt = 0; nt < 4; nt++) bb[nt] = *(const bf16x8*)&Bs[cn + nt * 16 + lm][lk];
#pragma unroll
    for (int mt = 0; mt < 4; mt++)
#pragma unroll
      for (int nt = 0; nt < 4; nt++) {
        acc[mt][nt] = __builtin_amdgcn_mfma_f32_16x16x32_bf16(ah[mt], bb[nt], acc[mt][nt], 0, 0, 0);
        if (!ABF)
          acc[mt][nt] = __builtin_amdgcn_mfma_f32_16x16x32_bf16(al[mt], bb[nt], acc[mt][nt], 0, 0, 0);
      }
    __syncthreads();
  }

  if (SPLIT) {
    short* epi = (short*)&As[0][0];   // 128*64 shorts = 16 KB
    if (wn == 0) {
#pragma unroll
      for (int mt = 0; mt < 4; mt++) {
        int lr = rm + mt * 16 + (lane >> 4) * 4;
#pragma unroll
        for (int r = 0; r < 4; r++) {
          int gr = row0 + lr + r;
          float sc = (SCL && gr < M) ? scl[gr] : 0.f;
#pragma unroll
          for (int nt = 0; nt < 4; nt++)
            epi[(lr + r) * 64 + nt * 16 + lm] = (short)f2bf(acc[mt][nt][r] * sc);
        }
      }
    } else {
#pragma unroll
      for (int mt = 0; mt < 4; mt++) {
        int grb = row0 + rm + mt * 16 + (lane >> 4) * 4;
#pragma unroll
        for (int nt = 0; nt < 4; nt++) {
          int gc = nt * 16 + lm;
          float bv = bias[gc];
#pragma unroll
          for (int r = 0; r < 4; r++) {
            int gr = grb + r;
            if (gr < M) ((float*)Cv2)[(size_t)gr * 64 + gc] = acc[mt][nt][r] + bv;
          }
        }
      }
    }
    __syncthreads();
    int base = tid * 32;
    int row = base >> 6, col = base & 63;
    int gr = row0 + row;
    if (gr < M) {
#pragma unroll
      for (int q = 0; q < 4; q++)
        *(bf16x8*)((short*)Cv + (size_t)gr * 64 + col + q * 8) = *(bf16x8*)&epi[base + q * 8];
    }
  } else if (OBF && WM == 1) {
    short* epi = &Bs[0][0];
    const int NCOL = 64 * WN;
    float bvv[4];
#pragma unroll
    for (int nt = 0; nt < 4; nt++) bvv[nt] = BIAS ? bias[col0 + cn + nt * 16 + lm] : 0.f;
#pragma unroll
    for (int mt = 0; mt < 4; mt++) {
      __syncthreads();
#pragma unroll
      for (int r = 0; r < 4; r++) {
        int gr = row0 + mt * 16 + (lane >> 4) * 4 + r;
        float sc = (SCL && gr < M) ? scl[gr] : 1.f;
#pragma unroll
        for (int nt = 0; nt < 4; nt++) {
          float v = acc[mt][nt][r] + bvv[nt];
          if (RELU) v = (v >= 0.f) ? v : 0.01f * v;
          if (SCL) v *= sc;
          epi[((lane >> 4) * 4 + r) * NCOL + cn + nt * 16 + lm] = (short)f2bf(v);
        }
      }
      __syncthreads();
      const int per = (16 * NCOL) / 256;
      int base = tid * per;
      int lr = base / NCOL, lc = base % NCOL;
      int gr = row0 + mt * 16 + lr;
      if (gr < M) {
#pragma unroll
        for (int q = 0; q < per / 8; q++)
          *(bf16x8*)((short*)Cv + (size_t)gr * NTOT + col0 + lc + q * 8) = *(bf16x8*)&epi[base + q * 8];
      }
    }
  } else {
#pragma unroll
    for (int mt = 0; mt < 4; mt++) {
      int grb = row0 + rm + mt * 16 + (lane >> 4) * 4;
#pragma unroll
      for (int nt = 0; nt < 4; nt++) {
        int gc = col0 + cn + nt * 16 + lm;
        float bv = BIAS ? bias[gc] : 0.f;
#pragma unroll
        for (int r = 0; r < 4; r++) {
          int gr = grb + r;
          if (gr < M) {
            float v = acc[mt][nt][r] + bv;
            if (RELU) v = (v >= 0.f) ? v : 0.01f * v;
            if (SCL) v *= scl[gr];
            if (OBF) ((short*)Cv)[(size_t)gr * NTOT + gc] = (short)f2bf(v);
            else     ((float*)Cv)[(size_t)gr * NTOT + gc] = v;
          }
        }
      }
    }
  }
}

// ------- fused layer3+layer4 (ping-pong LDS, bf16 out; measured plateau ~43 us) -------

__global__ __launch_bounds__(256, 3) void fused34_k(const short* __restrict__ z3,
                                                    const short* __restrict__ W3c,  // [512][256] bf16
                                                    const float* __restrict__ b3,
                                                    const short* __restrict__ W4c,  // [64][512] bf16
                                                    const float* __restrict__ dis,
                                                    short* __restrict__ T4, int M) {
  __shared__ short Bs[2][32][264];
  __shared__ short Ws4[2][64][40];
  __shared__ short Hs[64][40];
  const int tid = threadIdx.x;
  const int row0 = blockIdx.x * 64;
  const int w = tid >> 6, lane = tid & 63;
  const int lm = lane & 15, lk = (lane >> 4) * 8;
  const int rquad = (lane >> 4) * 4;
  const int w4row = tid >> 2, w4seg = (tid & 3) * 8;

  bf16x8 afr[8];
  {
    int gr = row0 + w * 16 + lm;
    bool ok = gr < M;
    const short* zp = z3 + (size_t)gr * 256 + lk;
#pragma unroll
    for (int kc = 0; kc < 8; kc++) {
      bf16x8 v = {0, 0, 0, 0, 0, 0, 0, 0};
      if (ok) v = *(const bf16x8*)(zp + kc * 32);
      afr[kc] = v;
    }
  }

  f32x4 t4acc[4];
#pragma unroll
  for (int nt = 0; nt < 4; nt++)
#pragma unroll
    for (int r = 0; r < 4; r++) t4acc[nt][r] = 0.f;

  bf16x8 pw3[4];
  bf16x8 pw4;
#pragma unroll
  for (int q = 0; q < 4; q++) {
    int flat = q * 2048 + tid * 8;
    pw3[q] = *(const bf16x8*)(W3c + flat);
  }
  pw4 = *(const bf16x8*)(W4c + (size_t)w4row * 512 + w4seg);
#pragma unroll
  for (int q = 0; q < 4; q++) {
    int flat = q * 2048 + tid * 8;
    *(bf16x8*)&Bs[0][flat >> 8][flat & 255] = pw3[q];
  }
  *(bf16x8*)&Ws4[0][w4row][w4seg] = pw4;
  __syncthreads();

  for (int c = 0; c < 16; c++) {
    int cur = c & 1, nxt = cur ^ 1;
    if (c < 15) {
#pragma unroll
      for (int q = 0; q < 4; q++) {
        int flat = q * 2048 + tid * 8;
        pw3[q] = *(const bf16x8*)(W3c + (size_t)(c + 1) * 32 * 256 + flat);
      }
      pw4 = *(const bf16x8*)(W4c + (size_t)w4row * 512 + (c + 1) * 32 + w4seg);
    }

    f32x4 acc1[2];
#pragma unroll
    for (int nt = 0; nt < 2; nt++)
#pragma unroll
      for (int r = 0; r < 4; r++) acc1[nt][r] = 0.f;
#pragma unroll
    for (int k0 = 0; k0 < 8; k0++) {
      bf16x8 bb[2];
#pragma unroll
      for (int nt = 0; nt < 2; nt++) bb[nt] = *(const bf16x8*)&Bs[cur][nt * 16 + lm][k0 * 32 + lk];
#pragma unroll
      for (int nt = 0; nt < 2; nt++)
        acc1[nt] = __builtin_amdgcn_mfma_f32_16x16x32_bf16(afr[k0], bb[nt], acc1[nt], 0, 0, 0);
    }
#pragma unroll
    for (int nt = 0; nt < 2; nt++) {
      float bv = b3[c * 32 + nt * 16 + lm];
#pragma unroll
      for (int r = 0; r < 4; r++) {
        float v = acc1[nt][r] + bv;
        v = (v >= 0.f) ? v : 0.01f * v;
        Hs[w * 16 + rquad + r][nt * 16 + lm] = (short)f2bf(v);
      }
    }
    {
      bf16x8 ah2 = *(const bf16x8*)&Hs[w * 16 + lm][lk];
      bf16x8 bb2[4];
#pragma unroll
      for (int nt = 0; nt < 4; nt++) bb2[nt] = *(const bf16x8*)&Ws4[cur][nt * 16 + lm][lk];
#pragma unroll
      for (int nt = 0; nt < 4; nt++)
        t4acc[nt] = __builtin_amdgcn_mfma_f32_16x16x32_bf16(ah2, bb2[nt], t4acc[nt], 0, 0, 0);
    }
    if (c < 15) {
#pragma unroll
      for (int q = 0; q < 4; q++) {
        int flat = q * 2048 + tid * 8;
        *(bf16x8*)&Bs[nxt][flat >> 8][flat & 255] = pw3[q];
      }
      *(bf16x8*)&Ws4[nxt][w4row][w4seg] = pw4;
    }
    __syncthreads();
  }
  short* epi = (short*)&Bs[0][0][0];   // 64*64 shorts = 8 KB
#pragma unroll
  for (int r = 0; r < 4; r++) {
    int lr = w * 16 + rquad + r;
    int gr = row0 + lr;
    float sc = (gr < M) ? dis[gr] : 0.f;
#pragma unroll
    for (int nt = 0; nt < 4; nt++)
      epi[lr * 64 + nt * 16 + lm] = (short)f2bf(t4acc[nt][r] * sc);
  }
  __syncthreads();
  {
    int base = tid * 16;
    int row = base >> 6, col = base & 63;
    int gr = row0 + row;
    if (gr < M) {
      *(bf16x8*)(T4 + (size_t)gr * 64 + col)     = *(bf16x8*)&epi[base];
      *(bf16x8*)(T4 + (size_t)gr * 64 + col + 8) = *(bf16x8*)&epi[base + 8];
    }
  }
}

// ------- Aggregation (dis-free; rows pre-scaled). Half-wave: 2 nodes/wave. -------

template<int BR, int OSCL>
__global__ __launch_bounds__(256) void aggb64_k(const short* __restrict__ T, const float* __restrict__ dis,
                                                const int* __restrict__ off, const int* __restrict__ csr,
                                                const float* __restrict__ bias, short* __restrict__ Out, int n) {
  int wv = (blockIdx.x * 256 + threadIdx.x) >> 6;
  int lane = threadIdx.x & 63;
  int half = lane >> 5, hl = lane & 31;
  int wid = wv * 2 + half;
  if (wid >= n) return;
  float di = dis[wid];
  int e0 = off[wid], e1 = off[wid + 1];
  const unsigned* Tw = (const unsigned*)T;
  unsigned su = Tw[(size_t)wid * 32 + hl];
  float a0 = bflo(su), a1 = bfhi(su);
  int e = e0;
  for (; e + 8 <= e1; e += 8) {
    int j0 = csr[e], j1 = csr[e + 1], j2 = csr[e + 2], j3 = csr[e + 3];
    int j4 = csr[e + 4], j5 = csr[e + 5], j6 = csr[e + 6], j7 = csr[e + 7];
    unsigned u0 = Tw[(size_t)j0 * 32 + hl];
    unsigned u1 = Tw[(size_t)j1 * 32 + hl];
    unsigned u2 = Tw[(size_t)j2 * 32 + hl];
    unsigned u3 = Tw[(size_t)j3 * 32 + hl];
    unsigned u4 = Tw[(size_t)j4 * 32 + hl];
    unsigned u5 = Tw[(size_t)j5 * 32 + hl];
    unsigned u6 = Tw[(size_t)j6 * 32 + hl];
    unsigned u7 = Tw[(size_t)j7 * 32 + hl];
    a0 += ((bflo(u0) + bflo(u1)) + (bflo(u2) + bflo(u3))) + ((bflo(u4) + bflo(u5)) + (bflo(u6) + bflo(u7)));
    a1 += ((bfhi(u0) + bfhi(u1)) + (bfhi(u2) + bfhi(u3))) + ((bfhi(u4) + bfhi(u5)) + (bfhi(u6) + bfhi(u7)));
  }
  for (; e + 4 <= e1; e += 4) {
    int j0 = csr[e], j1 = csr[e + 1], j2 = csr[e + 2], j3 = csr[e + 3];
    unsigned u0 = Tw[(size_t)j0 * 32 + hl];
    unsigned u1 = Tw[(size_t)j1 * 32 + hl];
    unsigned u2 = Tw[(size_t)j2 * 32 + hl];
    unsigned u3 = Tw[(size_t)j3 * 32 + hl];
    a0 += (bflo(u0) + bflo(u1)) + (bflo(u2) + bflo(u3));
    a1 += (bfhi(u0) + bfhi(u1)) + (bfhi(u2) + bfhi(u3));
  }
  for (; e < e1; e++) {
    unsigned u = Tw[(size_t)csr[e] * 32 + hl];
    a0 += bflo(u);
    a1 += bfhi(u);
  }
  float v0 = di * a0, v1 = di * a1;
  if (BR) {
    v0 += bias[hl * 2];
    v1 += bias[hl * 2 + 1];
    v0 = (v0 >= 0.f) ? v0 : 0.01f * v0;
    v1 = (v1 >= 0.f) ? v1 : 0.01f * v1;
  }
  if (OSCL) { v0 *= di; v1 *= di; }
  unsigned o = (unsigned)f2bf(v0) | ((unsigned)f2bf(v1) << 16);
  ((unsigned*)Out)[(size_t)wid * 32 + hl] = o;
}

// layer-4 tail (half-wave dual-node): hn = LN( leaky(di*sum(t4b) + b4) + resid )
// 32-lane LN reduction per half-wave (shfl offsets <32 stay within the half).
__global__ __launch_bounds__(256) void agg64_ln_k(const short* __restrict__ T, const float* __restrict__ dis,
                                                  const int* __restrict__ off, const int* __restrict__ csr,
                                                  const float* __restrict__ bias, const float* __restrict__ resid,
                                                  const float* __restrict__ g, const float* __restrict__ b,
                                                  float* __restrict__ outh, int n) {
  int wv = (blockIdx.x * 256 + threadIdx.x) >> 6;
  int lane = threadIdx.x & 63;
  int half = lane >> 5, hl = lane & 31;
  int wid = wv * 2 + half;
  if (wid >= n) return;
  float di = dis[wid];
  int e0 = off[wid], e1 = off[wid + 1];
  const unsigned* Tw = (const unsigned*)T;
  unsigned su = Tw[(size_t)wid * 32 + hl];
  float a0 = bflo(su), a1 = bfhi(su);
  int e = e0;
  for (; e + 8 <= e1; e += 8) {
    int j0 = csr[e], j1 = csr[e + 1], j2 = csr[e + 2], j3 = csr[e + 3];
    int j4 = csr[e + 4], j5 = csr[e + 5], j6 = csr[e + 6], j7 = csr[e + 7];
    unsigned u0 = Tw[(size_t)j0 * 32 + hl];
    unsigned u1 = Tw[(size_t)j1 * 32 + hl];
    unsigned u2 = Tw[(size_t)j2 * 32 + hl];
    unsigned u3 = Tw[(size_t)j3 * 32 + hl];
    unsigned u4 = Tw[(size_t)j4 * 32 + hl];
    unsigned u5 = Tw[(size_t)j5 * 32 + hl];
    unsigned u6 = Tw[(size_t)j6 * 32 + hl];
    unsigned u7 = Tw[(size_t)j7 * 32 + hl];
    a0 += ((bflo(u0) + bflo(u1)) + (bflo(u2) + bflo(u3))) + ((bflo(u4) + bflo(u5)) + (bflo(u6) + bflo(u7)));
    a1 += ((bfhi(u0) + bfhi(u1)) + (bfhi(u2) + bfhi(u3))) + ((bfhi(u4) + bfhi(u5)) + (bfhi(u6) + bfhi(u7)));
  }
  for (; e + 4 <= e1; e += 4) {
    int j0 = csr[e], j1 = csr[e + 1], j2 = csr[e + 2], j3 = csr[e + 3];
    unsigned u0 = Tw[(size_t)j0 * 32 + hl];
    unsigned u1 = Tw[(size_t)j1 * 32 + hl];
    unsigned u2 = Tw[(size_t)j2 * 32 + hl];
    unsigned u3 = Tw[(size_t)j3 * 32 + hl];
    a0 += (bflo(u0) + bflo(u1)) + (bflo(u2) + bflo(u3));
    a1 += (bfhi(u0) + bfhi(u1)) + (bfhi(u2) + bfhi(u3));
  }
  for (; e < e1; e++) {
    unsigned u = Tw[(size_t)csr[e] * 32 + hl];
    a0 += bflo(u);
    a1 += bfhi(u);
  }
  float2 rv = ((const float2*)resid)[(size_t)wid * 32 + hl];
  float v0 = di * a0 + bias[hl * 2];
  float v1 = di * a1 + bias[hl * 2 + 1];
  v0 = (v0 >= 0.f) ? v0 : 0.01f * v0;
  v1 = (v1 >= 0.f) ? v1 : 0.01f * v1;
  v0 += rv.x;
  v1 += rv.y;
  float s = v0 + v1, ss = v0 * v0 + v1 * v1;
#pragma unroll
  for (int o = 16; o > 0; o >>= 1) {
    s += __shfl_xor(s, o);
    ss += __shfl_xor(ss, o);
  }
  float m = s * (1.f / 64.f);
  float var = ss * (1.f / 64.f) - m * m;
  float rs = rsqrtf(var + 1e-5f);
  float2 o2;
  o2.x = (v0 - m) * rs * g[hl * 2] + b[hl * 2];
  o2.y = (v1 - m) * rs * g[hl * 2 + 1] + b[hl * 2 + 1];
  ((float2*)outh)[(size_t)wid * 32 + hl] = o2;
}

// 256-dim bf16 gather, half-wave dual-node: lane covers 8 features (16B)
__global__ __launch_bounds__(256) void agg256b_k(const short* __restrict__ T, const float* __restrict__ dis,
                                                 const int* __restrict__ off, const int* __restrict__ csr,
                                                 short* __restrict__ Out, int n) {
  int wv = (blockIdx.x * 256 + threadIdx.x) >> 6;
  int lane = threadIdx.x & 63;
  int half = lane >> 5, hl = lane & 31;
  int wid = wv * 2 + half;
  if (wid >= n) return;
  float di = dis[wid];
  int e0 = off[wid], e1 = off[wid + 1];
  bf16x8 sf = *(const bf16x8*)&T[(size_t)wid * 256 + hl * 8];
  float a[8];
#pragma unroll
  for (int q = 0; q < 8; q++) a[q] = bf2f((unsigned short)sf[q]);
  int e = e0;
  for (; e + 4 <= e1; e += 4) {
    bf16x8 t0 = *(const bf16x8*)&T[(size_t)csr[e] * 256 + hl * 8];
    bf16x8 t1 = *(const bf16x8*)&T[(size_t)csr[e + 1] * 256 + hl * 8];
    bf16x8 t2 = *(const bf16x8*)&T[(size_t)csr[e + 2] * 256 + hl * 8];
    bf16x8 t3 = *(const bf16x8*)&T[(size_t)csr[e + 3] * 256 + hl * 8];
#pragma unroll
    for (int q = 0; q < 8; q++)
      a[q] += (bf2f((unsigned short)t0[q]) + bf2f((unsigned short)t1[q])) +
              (bf2f((unsigned short)t2[q]) + bf2f((unsigned short)t3[q]));
  }
  for (; e < e1; e++) {
    bf16x8 t = *(const bf16x8*)&T[(size_t)csr[e] * 256 + hl * 8];
#pragma unroll
    for (int q = 0; q < 8; q++) a[q] += bf2f((unsigned short)t[q]);
  }
  bf16x8 o;
#pragma unroll
  for (int q = 0; q < 8; q++) o[q] = (short)f2bf(di * a[q]);
  *(bf16x8*)&Out[(size_t)wid * 256 + hl * 8] = o;
}

// ---------------- per-graph max pool + final MLP (fused, one block per graph) ----------------

__global__ __launch_bounds__(256) void pool_mlp_k(const float* __restrict__ hn,
                                                  const float* __restrict__ fc1W, const float* __restrict__ fc1b,
                                                  const float* __restrict__ fng, const float* __restrict__ fnb,
                                                  const float* __restrict__ fc2W, const float* __restrict__ fc2b,
                                                  float* __restrict__ out, int n) {
  const int G = 64;
  int g = blockIdx.x;
  int f = threadIdx.x & 63, c = threadIdx.x >> 6;
  long long s0 = ((long long)g * n + G - 1) / G;
  long long e0 = ((long long)(g + 1) * n + G - 1) / G;
  float m = -INFINITY;
  for (long long i = s0 + c; i < e0; i += 4) m = fmaxf(m, hn[(size_t)i * 64 + f]);
  __shared__ float red[4][64];
  __shared__ float ps[64], qs[64];
  red[c][f] = m;
  __syncthreads();
  if (c == 0) ps[f] = fmaxf(fmaxf(red[0][f], red[1][f]), fmaxf(red[2][f], red[3][f]));
  __syncthreads();
  if (threadIdx.x < 64) {
    int lane = threadIdx.x;
    float q = fc1b[lane];
#pragma unroll 8
    for (int k = 0; k < 64; k++) q = fmaf(ps[k], fc1W[k * 64 + lane], q);
    float s = q, ss = q * q;
#pragma unroll
    for (int o = 32; o > 0; o >>= 1) {
      s += __shfl_xor(s, o);
      ss += __shfl_xor(ss, o);
    }
    float mm = s * (1.f / 64.f);
    float var = ss * (1.f / 64.f) - mm * mm;
    float y = (q - mm) * rsqrtf(var + 1e-5f) * fng[lane] + fnb[lane];
    y = (y >= 0.f) ? y : 0.01f * y;
    qs[lane] = y;
    __builtin_amdgcn_wave_barrier();
    if (lane < 16) {
      float o = fc2b[lane];
#pragma unroll 8
      for (int k = 0; k < 64; k++) o = fmaf(qs[k], fc2W[k * 16 + lane], o);
      out[g * 16 + lane] = o;
    }
  }
}

// ---------------- launch ----------------

extern "C" void kernel_launch(void* const* d_in, const int* in_sizes, int n_in,
                              void* d_out, int out_size, void* d_ws, size_t ws_size,
                              hipStream_t stream) {
  const float* x   = (const float*)d_in[0];
  const int*   ei  = (const int*)d_in[1];
  const float* W1  = (const float*)d_in[3];
  const float* b1  = (const float*)d_in[4];
  const float* W2  = (const float*)d_in[5];
  const float* b2  = (const float*)d_in[6];
  const float* W3  = (const float*)d_in[7];
  const float* b3  = (const float*)d_in[8];
  const float* W4  = (const float*)d_in[9];
  const float* b4  = (const float*)d_in[10];
  const float* Wr  = (const float*)d_in[11];
  const float* br  = (const float*)d_in[12];
  const float* lng = (const float*)d_in[13];
  const float* lnb = (const float*)d_in[14];
  const float* f1W = (const float*)d_in[15];
  const float* f1b = (const float*)d_in[16];
  const float* fng = (const float*)d_in[17];
  const float* fnb = (const float*)d_in[18];
  const float* f2W = (const float*)d_in[19];
  const float* f2b = (const float*)d_in[20];

  int n = in_sizes[0] / 128;   // 50000
  int e = in_sizes[1] / 2;     // 400000
  const int* src = ei;
  const int* dst = ei + e;

  float* arena = (float*)d_ws;
  float* resid = arena;
  short* h2b   = (short*)(arena + (size_t)64 * n);
  short* t4b   = (short*)(arena + (size_t)64 * n);   // n x 64 bf16; h2b dead when written
  short* z3b   = (short*)(arena + (size_t)192 * n);
  float* hn    = arena + (size_t)192 * n;
  short* t1b   = (short*)(arena + (size_t)320 * n);
  short* h1b   = (short*)(arena + (size_t)352 * n);
  short* z2b   = (short*)(arena + (size_t)384 * n);
  float* dis   = arena + (size_t)448 * n;  // n
  int* cnt    = (int*)(dis + n);           // n
  int* off    = cnt + n;                   // n+1
  int* cursor = off + n + 1;               // n
  int* csr    = cursor + n;                // e
  int* bsum   = csr + e;                   // 256
  int* bpre   = bsum + 256;                // 256
  float* pool = (float*)(bpre + 256);      // layout keep
  size_t wq = (((size_t)(pool + 4096)) + 15) & ~(size_t)15;
  short* wc1 = (short*)wq;                 // 64 x 128   (wc1||wcR = fused 128 x 128)
  short* wcR = wc1 + 8192;                 // 64 x 128
  short* wc2 = wcR + 8192;                 // 256 x 64
  short* wc3 = wc2 + 16384;                // 512 x 256
  short* wc4 = wc3 + 131072;               // 64 x 512
  size_t need = ((char*)(wc4 + 32768) - (char*)d_ws) + 64;
  if (ws_size < need) return;

  int nb_n = (n + 255) / 256;        // 196
  int nb_e = (e + 255) / 256;
  int nb_w2 = ((n + 1) / 2 + 3) / 4; // two nodes per wave
  int g_wide = (n + 63) / 64;        // 782
  int g_fused = (n + 127) / 128;     // 391

  // weights -> bf16 [N][K]
  wconv_k<<<960, 256, 0, stream>>>(W1, Wr, W2, W3, W4, wc1, wcR, wc2, wc3, wc4);

  // degree + CSR (hierarchical scan; dis fused into scan_c)
  hipMemsetAsync(cnt, 0, (size_t)n * sizeof(int), stream);
  count_k<<<nb_e, 256, 0, stream>>>(dst, cnt, e);
  scan_a<<<nb_n, 256, 0, stream>>>(cnt, bsum, n);
  scan_b<<<1, 256, 0, stream>>>(bsum, bpre, off + n, nb_n);
  scan_c<<<nb_n, 256, 0, stream>>>(cnt, bpre, off, cursor, dis, n);
  scatter_k<<<nb_e, 256, 0, stream>>>(src, dst, cursor, csr, e);

  // fused L1 + residual: t1b = bf16(dis*(x@W1)); resid = x@Wr + br
  mgemm<128, 128, 2, 2, 1, 0, 0, 0, 1, 1, 4><<<dim3(g_fused, 1), 256, 0, stream>>>(x, wc1, br, t1b, resid, dis, n);
  // h1b = bf16( dis * leaky(di*sum(t1) + b1) )
  aggb64_k<1, 1><<<nb_w2, 256, 0, stream>>>(t1b, dis, off, csr, b1, h1b, n);
  // z2b = bf16( di * sum(h1) )
  aggb64_k<0, 0><<<nb_w2, 256, 0, stream>>>(h1b, dis, off, csr, nullptr, z2b, n);
  // h2b = bf16( dis * leaky(z2@W2 + b2) )
  mgemm<64, 256, 1, 4, 1, 1, 1, 1, 0, 1, 5><<<dim3(g_wide, 1), 256, 0, stream>>>(z2b, wc2, b2, h2b, nullptr, dis, n);
  // z3b = bf16( di * sum(h2b) )
  agg256b_k<<<nb_w2, 256, 0, stream>>>(h2b, dis, off, csr, z3b, n);
  // t4b = bf16( dis * (leaky(z3@W3+b3) @ W4) )   (h3 on-chip, ping-pong)
  fused34_k<<<g_wide, 256, 0, stream>>>(z3b, wc3, b3, wc4, dis, t4b, n);
  // hn = LN( leaky(di*sum(t4b) + b4) + resid )   (half-wave dual-node)
  agg64_ln_k<<<nb_w2, 256, 0, stream>>>(t4b, dis, off, csr, b4, resid, lng, lnb, hn, n);
  // pool + MLP fused
  pool_mlp_k<<<64, 256, 0, stream>>>(hn, f1W, f1b, fng, fnb, f2W, f2b, (float*)d_out, n);
}

// Round 19
// 350.685 us; speedup vs baseline: 1.1875x; 1.0185x over previous
//
#include <hip/hip_runtime.h>
#include <hip/hip_bf16.h>
#include <math.h>

typedef short bf16x8 __attribute__((ext_vector_type(8)));
typedef short bf16x4 __attribute__((ext_vector_type(4)));
typedef float f32x4 __attribute__((ext_vector_type(4)));

__device__ inline unsigned short f2bf(float f) {
  unsigned u = __float_as_uint(f);
  u += 0x7FFF + ((u >> 16) & 1);           // RNE
  return (unsigned short)(u >> 16);
}
__device__ inline float bf2f(unsigned short h) {
  return __uint_as_float(((unsigned)h) << 16);
}
__device__ inline float bflo(unsigned u) { return __uint_as_float(u << 16); }
__device__ inline float bfhi(unsigned u) { return __uint_as_float(u & 0xffff0000u); }

// ---------------- CSR build ----------------

__global__ __launch_bounds__(256) void count_k(const int* __restrict__ dst, int* __restrict__ cnt, int e) {
  int i = blockIdx.x * 256 + threadIdx.x;
  if (i < e) atomicAdd(&cnt[dst[i]], 1);
}

__global__ __launch_bounds__(256) void scan_a(const int* __restrict__ cnt, int* __restrict__ bsum, int n) {
  int i = blockIdx.x * 256 + threadIdx.x;
  int v = (i < n) ? cnt[i] : 0;
#pragma unroll
  for (int o = 32; o > 0; o >>= 1) v += __shfl_xor(v, o);
  __shared__ int ws[4];
  if ((threadIdx.x & 63) == 0) ws[threadIdx.x >> 6] = v;
  __syncthreads();
  if (threadIdx.x == 0) bsum[blockIdx.x] = ws[0] + ws[1] + ws[2] + ws[3];
}

__global__ __launch_bounds__(256) void scan_b(const int* __restrict__ bsum, int* __restrict__ bpre,
                                              int* __restrict__ off_n, int nb) {
  __shared__ int s[256];
  int t = threadIdx.x;
  int v = (t < nb) ? bsum[t] : 0;
  s[t] = v;
  __syncthreads();
  for (int o = 1; o < 256; o <<= 1) {
    int u = (t >= o) ? s[t - o] : 0;
    __syncthreads();
    s[t] += u;
    __syncthreads();
  }
  if (t < nb) bpre[t] = s[t] - v;
  if (t == 255) off_n[0] = s[255];
}

// scan_c also computes dis = rsqrt(cnt+1)
__global__ __launch_bounds__(256) void scan_c(const int* __restrict__ cnt, const int* __restrict__ bpre,
                                              int* __restrict__ off, int* __restrict__ cursor,
                                              float* __restrict__ dis, int n) {
  __shared__ int s[256];
  int i = blockIdx.x * 256 + threadIdx.x;
  int t = threadIdx.x;
  int v = (i < n) ? cnt[i] : 0;
  s[t] = v;
  __syncthreads();
  for (int o = 1; o < 256; o <<= 1) {
    int u = (t >= o) ? s[t - o] : 0;
    __syncthreads();
    s[t] += u;
    __syncthreads();
  }
  if (i < n) {
    int ov = bpre[blockIdx.x] + s[t] - v;
    off[i] = ov;
    cursor[i] = ov;
    dis[i] = rsqrtf((float)v + 1.0f);
  }
}

__global__ __launch_bounds__(256) void scatter_k(const int* __restrict__ src, const int* __restrict__ dst,
                                                 int* __restrict__ cursor, int* __restrict__ csr, int e) {
  int i = blockIdx.x * 256 + threadIdx.x;
  if (i < e) {
    int p = atomicAdd(&cursor[dst[i]], 1);
    csr[p] = src[i];
  }
}

// ------- weight convert: W[K][N] fp32 -> Wc[N][K] bf16 -------

__global__ __launch_bounds__(256) void wconv_k(const float* __restrict__ W1, const float* __restrict__ Wr,
                                               const float* __restrict__ W2, const float* __restrict__ W3,
                                               const float* __restrict__ W4,
                                               short* __restrict__ o1, short* __restrict__ oR,
                                               short* __restrict__ o2, short* __restrict__ o3,
                                               short* __restrict__ o4) {
  int b = blockIdx.x;  // 960 rows total
  const float* W; short* O; int K, N, nr;
  if (b < 64)       { W = W1; O = o1; K = 128; N = 64;  nr = b; }
  else if (b < 128) { W = Wr; O = oR; K = 128; N = 64;  nr = b - 64; }
  else if (b < 384) { W = W2; O = o2; K = 64;  N = 256; nr = b - 128; }
  else if (b < 896) { W = W3; O = o3; K = 256; N = 512; nr = b - 384; }
  else              { W = W4; O = o4; K = 512; N = 64;  nr = b - 896; }
  for (int k = threadIdx.x; k < K; k += 256)
    O[(size_t)nr * K + k] = (short)f2bf(W[(size_t)k * N + nr]);
}

// ------- MFMA GEMM (generic): C[M,NTOT] = A[M,KT] @ Wc[NTOT,KT](bf16) -------

template<int KT, int NTOT, int WM, int WN, int BIAS, int RELU, int ABF, int OBF, int SPLIT, int SCL, int BLK>
__global__ __launch_bounds__(256, BLK) void mgemm(const void* __restrict__ Av,
                                                  const short* __restrict__ Wc,
                                                  const float* __restrict__ bias,
                                                  void* __restrict__ Cv, void* __restrict__ Cv2,
                                                  const float* __restrict__ scl, int M) {
  __shared__ short As[64 * WM][ABF ? 40 : 72];
  __shared__ short Bs[64 * WN][40];
  const int tid = threadIdx.x;
  const int row0 = blockIdx.x * (64 * WM);
  const int col0 = blockIdx.y * (64 * WN);
  const int w = tid >> 6, lane = tid & 63;
  const int wm = w / WN, wn = w % WN;
  const int rm = wm * 64, cn = wn * 64;
  const int lm = lane & 15, lk = (lane >> 4) * 8;

  f32x4 acc[4][4];
#pragma unroll
  for (int i = 0; i < 4; i++)
#pragma unroll
    for (int j = 0; j < 4; j++)
#pragma unroll
      for (int r = 0; r < 4; r++) acc[i][j][r] = 0.f;

  for (int k0 = 0; k0 < KT; k0 += 32) {
#pragma unroll
    for (int p = 0; p < WM; p++) {
      int r = (tid >> 2) + p * 64;
      int kseg = (tid & 3) * 8;
      int gr = row0 + r;
      if (ABF) {
        bf16x8 v = {0, 0, 0, 0, 0, 0, 0, 0};
        if (gr < M) v = *(const bf16x8*)((const short*)Av + (size_t)gr * KT + k0 + kseg);
        *(bf16x8*)&As[r][kseg] = v;
      } else {
        float4 v0 = {0.f, 0.f, 0.f, 0.f}, v1 = {0.f, 0.f, 0.f, 0.f};
        if (gr < M) {
          const float* ap = (const float*)Av + (size_t)gr * KT + k0 + kseg;
          v0 = *(const float4*)ap;
          v1 = *(const float4*)(ap + 4);
        }
        float vv[8] = {v0.x, v0.y, v0.z, v0.w, v1.x, v1.y, v1.z, v1.w};
        bf16x8 hv, lv;
#pragma unroll
        for (int j = 0; j < 8; j++) {
          unsigned short h = f2bf(vv[j]);
          hv[j] = (short)h;
          lv[j] = (short)f2bf(vv[j] - bf2f(h));
        }
        *(bf16x8*)&As[r][kseg] = hv;
        *(bf16x8*)&As[r][32 + kseg] = lv;
      }
    }
#pragma unroll
    for (int p = 0; p < WN; p++) {
      int nr = (tid >> 2) + p * 64;
      int seg = (tid & 3) * 8;
      *(bf16x8*)&Bs[nr][seg] = *(const bf16x8*)(Wc + (size_t)(col0 + nr) * KT + k0 + seg);
    }
    __syncthreads();

    bf16x8 ah[4], al[4], bb[4];
#pragma unroll
    for (int mt = 0; mt < 4; mt++) {
      ah[mt] = *(const bf16x8*)&As[rm + mt * 16 + lm][lk];
      if (!ABF) al[mt] = *(const bf16x8*)&As[rm + mt * 16 + lm][32 + lk];
    }
#pragma unroll
    for (int nt = 0; nt < 4; nt++) bb[nt] = *(const bf16x8*)&Bs[cn + nt * 16 + lm][lk];
#pragma unroll
    for (int mt = 0; mt < 4; mt++)
#pragma unroll
      for (int nt = 0; nt < 4; nt++) {
        acc[mt][nt] = __builtin_amdgcn_mfma_f32_16x16x32_bf16(ah[mt], bb[nt], acc[mt][nt], 0, 0, 0);
        if (!ABF)
          acc[mt][nt] = __builtin_amdgcn_mfma_f32_16x16x32_bf16(al[mt], bb[nt], acc[mt][nt], 0, 0, 0);
      }
    __syncthreads();
  }

  if (SPLIT) {
    short* epi = (short*)&As[0][0];   // 128*64 shorts = 16 KB
    if (wn == 0) {
#pragma unroll
      for (int mt = 0; mt < 4; mt++) {
        int lr = rm + mt * 16 + (lane >> 4) * 4;
#pragma unroll
        for (int r = 0; r < 4; r++) {
          int gr = row0 + lr + r;
          float sc = (SCL && gr < M) ? scl[gr] : 0.f;
#pragma unroll
          for (int nt = 0; nt < 4; nt++)
            epi[(lr + r) * 64 + nt * 16 + lm] = (short)f2bf(acc[mt][nt][r] * sc);
        }
      }
    } else {
#pragma unroll
      for (int mt = 0; mt < 4; mt++) {
        int grb = row0 + rm + mt * 16 + (lane >> 4) * 4;
#pragma unroll
        for (int nt = 0; nt < 4; nt++) {
          int gc = nt * 16 + lm;
          float bv = bias[gc];
#pragma unroll
          for (int r = 0; r < 4; r++) {
            int gr = grb + r;
            if (gr < M) ((float*)Cv2)[(size_t)gr * 64 + gc] = acc[mt][nt][r] + bv;
          }
        }
      }
    }
    __syncthreads();
    int base = tid * 32;
    int row = base >> 6, col = base & 63;
    int gr = row0 + row;
    if (gr < M) {
#pragma unroll
      for (int q = 0; q < 4; q++)
        *(bf16x8*)((short*)Cv + (size_t)gr * 64 + col + q * 8) = *(bf16x8*)&epi[base + q * 8];
    }
  } else if (OBF && WM == 1) {
    short* epi = &Bs[0][0];
    const int NCOL = 64 * WN;
    float bvv[4];
#pragma unroll
    for (int nt = 0; nt < 4; nt++) bvv[nt] = BIAS ? bias[col0 + cn + nt * 16 + lm] : 0.f;
#pragma unroll
    for (int mt = 0; mt < 4; mt++) {
      __syncthreads();
#pragma unroll
      for (int r = 0; r < 4; r++) {
        int gr = row0 + mt * 16 + (lane >> 4) * 4 + r;
        float sc = (SCL && gr < M) ? scl[gr] : 1.f;
#pragma unroll
        for (int nt = 0; nt < 4; nt++) {
          float v = acc[mt][nt][r] + bvv[nt];
          if (RELU) v = (v >= 0.f) ? v : 0.01f * v;
          if (SCL) v *= sc;
          epi[((lane >> 4) * 4 + r) * NCOL + cn + nt * 16 + lm] = (short)f2bf(v);
        }
      }
      __syncthreads();
      const int per = (16 * NCOL) / 256;
      int base = tid * per;
      int lr = base / NCOL, lc = base % NCOL;
      int gr = row0 + mt * 16 + lr;
      if (gr < M) {
#pragma unroll
        for (int q = 0; q < per / 8; q++)
          *(bf16x8*)((short*)Cv + (size_t)gr * NTOT + col0 + lc + q * 8) = *(bf16x8*)&epi[base + q * 8];
      }
    }
  } else {
#pragma unroll
    for (int mt = 0; mt < 4; mt++) {
      int grb = row0 + rm + mt * 16 + (lane >> 4) * 4;
#pragma unroll
      for (int nt = 0; nt < 4; nt++) {
        int gc = col0 + cn + nt * 16 + lm;
        float bv = BIAS ? bias[gc] : 0.f;
#pragma unroll
        for (int r = 0; r < 4; r++) {
          int gr = grb + r;
          if (gr < M) {
            float v = acc[mt][nt][r] + bv;
            if (RELU) v = (v >= 0.f) ? v : 0.01f * v;
            if (SCL) v *= scl[gr];
            if (OBF) ((short*)Cv)[(size_t)gr * NTOT + gc] = (short)f2bf(v);
            else     ((float*)Cv)[(size_t)gr * NTOT + gc] = v;
          }
        }
      }
    }
  }
}

// ------- fused layer3+layer4 (ping-pong LDS, bf16 out; measured plateau ~43 us) -------

__global__ __launch_bounds__(256, 3) void fused34_k(const short* __restrict__ z3,
                                                    const short* __restrict__ W3c,  // [512][256] bf16
                                                    const float* __restrict__ b3,
                                                    const short* __restrict__ W4c,  // [64][512] bf16
                                                    const float* __restrict__ dis,
                                                    short* __restrict__ T4, int M) {
  __shared__ short Bs[2][32][264];
  __shared__ short Ws4[2][64][40];
  __shared__ short Hs[64][40];
  const int tid = threadIdx.x;
  const int row0 = blockIdx.x * 64;
  const int w = tid >> 6, lane = tid & 63;
  const int lm = lane & 15, lk = (lane >> 4) * 8;
  const int rquad = (lane >> 4) * 4;
  const int w4row = tid >> 2, w4seg = (tid & 3) * 8;

  bf16x8 afr[8];
  {
    int gr = row0 + w * 16 + lm;
    bool ok = gr < M;
    const short* zp = z3 + (size_t)gr * 256 + lk;
#pragma unroll
    for (int kc = 0; kc < 8; kc++) {
      bf16x8 v = {0, 0, 0, 0, 0, 0, 0, 0};
      if (ok) v = *(const bf16x8*)(zp + kc * 32);
      afr[kc] = v;
    }
  }

  f32x4 t4acc[4];
#pragma unroll
  for (int nt = 0; nt < 4; nt++)
#pragma unroll
    for (int r = 0; r < 4; r++) t4acc[nt][r] = 0.f;

  bf16x8 pw3[4];
  bf16x8 pw4;
#pragma unroll
  for (int q = 0; q < 4; q++) {
    int flat = q * 2048 + tid * 8;
    pw3[q] = *(const bf16x8*)(W3c + flat);
  }
  pw4 = *(const bf16x8*)(W4c + (size_t)w4row * 512 + w4seg);
#pragma unroll
  for (int q = 0; q < 4; q++) {
    int flat = q * 2048 + tid * 8;
    *(bf16x8*)&Bs[0][flat >> 8][flat & 255] = pw3[q];
  }
  *(bf16x8*)&Ws4[0][w4row][w4seg] = pw4;
  __syncthreads();

  for (int c = 0; c < 16; c++) {
    int cur = c & 1, nxt = cur ^ 1;
    if (c < 15) {
#pragma unroll
      for (int q = 0; q < 4; q++) {
        int flat = q * 2048 + tid * 8;
        pw3[q] = *(const bf16x8*)(W3c + (size_t)(c + 1) * 32 * 256 + flat);
      }
      pw4 = *(const bf16x8*)(W4c + (size_t)w4row * 512 + (c + 1) * 32 + w4seg);
    }

    f32x4 acc1[2];
#pragma unroll
    for (int nt = 0; nt < 2; nt++)
#pragma unroll
      for (int r = 0; r < 4; r++) acc1[nt][r] = 0.f;
#pragma unroll
    for (int k0 = 0; k0 < 8; k0++) {
      bf16x8 bb[2];
#pragma unroll
      for (int nt = 0; nt < 2; nt++) bb[nt] = *(const bf16x8*)&Bs[cur][nt * 16 + lm][k0 * 32 + lk];
#pragma unroll
      for (int nt = 0; nt < 2; nt++)
        acc1[nt] = __builtin_amdgcn_mfma_f32_16x16x32_bf16(afr[k0], bb[nt], acc1[nt], 0, 0, 0);
    }
#pragma unroll
    for (int nt = 0; nt < 2; nt++) {
      float bv = b3[c * 32 + nt * 16 + lm];
#pragma unroll
      for (int r = 0; r < 4; r++) {
        float v = acc1[nt][r] + bv;
        v = (v >= 0.f) ? v : 0.01f * v;
        Hs[w * 16 + rquad + r][nt * 16 + lm] = (short)f2bf(v);
      }
    }
    {
      bf16x8 ah2 = *(const bf16x8*)&Hs[w * 16 + lm][lk];
      bf16x8 bb2[4];
#pragma unroll
      for (int nt = 0; nt < 4; nt++) bb2[nt] = *(const bf16x8*)&Ws4[cur][nt * 16 + lm][lk];
#pragma unroll
      for (int nt = 0; nt < 4; nt++)
        t4acc[nt] = __builtin_amdgcn_mfma_f32_16x16x32_bf16(ah2, bb2[nt], t4acc[nt], 0, 0, 0);
    }
    if (c < 15) {
#pragma unroll
      for (int q = 0; q < 4; q++) {
        int flat = q * 2048 + tid * 8;
        *(bf16x8*)&Bs[nxt][flat >> 8][flat & 255] = pw3[q];
      }
      *(bf16x8*)&Ws4[nxt][w4row][w4seg] = pw4;
    }
    __syncthreads();
  }
  short* epi = (short*)&Bs[0][0][0];   // 64*64 shorts = 8 KB
#pragma unroll
  for (int r = 0; r < 4; r++) {
    int lr = w * 16 + rquad + r;
    int gr = row0 + lr;
    float sc = (gr < M) ? dis[gr] : 0.f;
#pragma unroll
    for (int nt = 0; nt < 4; nt++)
      epi[lr * 64 + nt * 16 + lm] = (short)f2bf(t4acc[nt][r] * sc);
  }
  __syncthreads();
  {
    int base = tid * 16;
    int row = base >> 6, col = base & 63;
    int gr = row0 + row;
    if (gr < M) {
      *(bf16x8*)(T4 + (size_t)gr * 64 + col)     = *(bf16x8*)&epi[base];
      *(bf16x8*)(T4 + (size_t)gr * 64 + col + 8) = *(bf16x8*)&epi[base + 8];
    }
  }
}

// ------- Aggregation (dis-free; rows pre-scaled). Quad-node: 4 nodes/wave. -------
// Lane quarter q -> node 4w+q; each lane covers 4 features (8B, uint2).

template<int BR, int OSCL>
__global__ __launch_bounds__(256) void aggb64_k(const short* __restrict__ T, const float* __restrict__ dis,
                                                const int* __restrict__ off, const int* __restrict__ csr,
                                                const float* __restrict__ bias, short* __restrict__ Out, int n) {
  int wv = (blockIdx.x * 256 + threadIdx.x) >> 6;
  int lane = threadIdx.x & 63;
  int qtr = lane >> 4, ql = lane & 15;
  int wid = wv * 4 + qtr;
  if (wid >= n) return;
  float di = dis[wid];
  int e0 = off[wid], e1 = off[wid + 1];
  const uint2* Tw = (const uint2*)T;   // 4 bf16 per uint2; row = 16 uint2
  uint2 su = Tw[(size_t)wid * 16 + ql];
  float a0 = bflo(su.x), a1 = bfhi(su.x), a2 = bflo(su.y), a3 = bfhi(su.y);
  int e = e0;
  for (; e + 8 <= e1; e += 8) {
    uint2 u0 = Tw[(size_t)csr[e]     * 16 + ql];
    uint2 u1 = Tw[(size_t)csr[e + 1] * 16 + ql];
    uint2 u2 = Tw[(size_t)csr[e + 2] * 16 + ql];
    uint2 u3 = Tw[(size_t)csr[e + 3] * 16 + ql];
    uint2 u4 = Tw[(size_t)csr[e + 4] * 16 + ql];
    uint2 u5 = Tw[(size_t)csr[e + 5] * 16 + ql];
    uint2 u6 = Tw[(size_t)csr[e + 6] * 16 + ql];
    uint2 u7 = Tw[(size_t)csr[e + 7] * 16 + ql];
    a0 += ((bflo(u0.x) + bflo(u1.x)) + (bflo(u2.x) + bflo(u3.x))) +
          ((bflo(u4.x) + bflo(u5.x)) + (bflo(u6.x) + bflo(u7.x)));
    a1 += ((bfhi(u0.x) + bfhi(u1.x)) + (bfhi(u2.x) + bfhi(u3.x))) +
          ((bfhi(u4.x) + bfhi(u5.x)) + (bfhi(u6.x) + bfhi(u7.x)));
    a2 += ((bflo(u0.y) + bflo(u1.y)) + (bflo(u2.y) + bflo(u3.y))) +
          ((bflo(u4.y) + bflo(u5.y)) + (bflo(u6.y) + bflo(u7.y)));
    a3 += ((bfhi(u0.y) + bfhi(u1.y)) + (bfhi(u2.y) + bfhi(u3.y))) +
          ((bfhi(u4.y) + bfhi(u5.y)) + (bfhi(u6.y) + bfhi(u7.y)));
  }
  for (; e + 4 <= e1; e += 4) {
    uint2 u0 = Tw[(size_t)csr[e]     * 16 + ql];
    uint2 u1 = Tw[(size_t)csr[e + 1] * 16 + ql];
    uint2 u2 = Tw[(size_t)csr[e + 2] * 16 + ql];
    uint2 u3 = Tw[(size_t)csr[e + 3] * 16 + ql];
    a0 += (bflo(u0.x) + bflo(u1.x)) + (bflo(u2.x) + bflo(u3.x));
    a1 += (bfhi(u0.x) + bfhi(u1.x)) + (bfhi(u2.x) + bfhi(u3.x));
    a2 += (bflo(u0.y) + bflo(u1.y)) + (bflo(u2.y) + bflo(u3.y));
    a3 += (bfhi(u0.y) + bfhi(u1.y)) + (bfhi(u2.y) + bfhi(u3.y));
  }
  for (; e < e1; e++) {
    uint2 u = Tw[(size_t)csr[e] * 16 + ql];
    a0 += bflo(u.x); a1 += bfhi(u.x); a2 += bflo(u.y); a3 += bfhi(u.y);
  }
  float v0 = di * a0, v1 = di * a1, v2 = di * a2, v3 = di * a3;
  if (BR) {
    v0 += bias[ql * 4];     v1 += bias[ql * 4 + 1];
    v2 += bias[ql * 4 + 2]; v3 += bias[ql * 4 + 3];
    v0 = (v0 >= 0.f) ? v0 : 0.01f * v0;
    v1 = (v1 >= 0.f) ? v1 : 0.01f * v1;
    v2 = (v2 >= 0.f) ? v2 : 0.01f * v2;
    v3 = (v3 >= 0.f) ? v3 : 0.01f * v3;
  }
  if (OSCL) { v0 *= di; v1 *= di; v2 *= di; v3 *= di; }
  uint2 o;
  o.x = (unsigned)f2bf(v0) | ((unsigned)f2bf(v1) << 16);
  o.y = (unsigned)f2bf(v2) | ((unsigned)f2bf(v3) << 16);
  ((uint2*)Out)[(size_t)wid * 16 + ql] = o;
}

// layer-4 tail (quad-node): hn = LN( leaky(di*sum(t4b) + b4) + resid )
// 16-lane LN reduction per quarter (shfl offsets 8/4/2/1 stay within the quarter).
__global__ __launch_bounds__(256) void agg64_ln_k(const short* __restrict__ T, const float* __restrict__ dis,
                                                  const int* __restrict__ off, const int* __restrict__ csr,
                                                  const float* __restrict__ bias, const float* __restrict__ resid,
                                                  const float* __restrict__ g, const float* __restrict__ b,
                                                  float* __restrict__ outh, int n) {
  int wv = (blockIdx.x * 256 + threadIdx.x) >> 6;
  int lane = threadIdx.x & 63;
  int qtr = lane >> 4, ql = lane & 15;
  int wid = wv * 4 + qtr;
  if (wid >= n) return;
  float di = dis[wid];
  int e0 = off[wid], e1 = off[wid + 1];
  const uint2* Tw = (const uint2*)T;
  uint2 su = Tw[(size_t)wid * 16 + ql];
  float a0 = bflo(su.x), a1 = bfhi(su.x), a2 = bflo(su.y), a3 = bfhi(su.y);
  int e = e0;
  for (; e + 8 <= e1; e += 8) {
    uint2 u0 = Tw[(size_t)csr[e]     * 16 + ql];
    uint2 u1 = Tw[(size_t)csr[e + 1] * 16 + ql];
    uint2 u2 = Tw[(size_t)csr[e + 2] * 16 + ql];
    uint2 u3 = Tw[(size_t)csr[e + 3] * 16 + ql];
    uint2 u4 = Tw[(size_t)csr[e + 4] * 16 + ql];
    uint2 u5 = Tw[(size_t)csr[e + 5] * 16 + ql];
    uint2 u6 = Tw[(size_t)csr[e + 6] * 16 + ql];
    uint2 u7 = Tw[(size_t)csr[e + 7] * 16 + ql];
    a0 += ((bflo(u0.x) + bflo(u1.x)) + (bflo(u2.x) + bflo(u3.x))) +
          ((bflo(u4.x) + bflo(u5.x)) + (bflo(u6.x) + bflo(u7.x)));
    a1 += ((bfhi(u0.x) + bfhi(u1.x)) + (bfhi(u2.x) + bfhi(u3.x))) +
          ((bfhi(u4.x) + bfhi(u5.x)) + (bfhi(u6.x) + bfhi(u7.x)));
    a2 += ((bflo(u0.y) + bflo(u1.y)) + (bflo(u2.y) + bflo(u3.y))) +
          ((bflo(u4.y) + bflo(u5.y)) + (bflo(u6.y) + bflo(u7.y)));
    a3 += ((bfhi(u0.y) + bfhi(u1.y)) + (bfhi(u2.y) + bfhi(u3.y))) +
          ((bfhi(u4.y) + bfhi(u5.y)) + (bfhi(u6.y) + bfhi(u7.y)));
  }
  for (; e + 4 <= e1; e += 4) {
    uint2 u0 = Tw[(size_t)csr[e]     * 16 + ql];
    uint2 u1 = Tw[(size_t)csr[e + 1] * 16 + ql];
    uint2 u2 = Tw[(size_t)csr[e + 2] * 16 + ql];
    uint2 u3 = Tw[(size_t)csr[e + 3] * 16 + ql];
    a0 += (bflo(u0.x) + bflo(u1.x)) + (bflo(u2.x) + bflo(u3.x));
    a1 += (bfhi(u0.x) + bfhi(u1.x)) + (bfhi(u2.x) + bfhi(u3.x));
    a2 += (bflo(u0.y) + bflo(u1.y)) + (bflo(u2.y) + bflo(u3.y));
    a3 += (bfhi(u0.y) + bfhi(u1.y)) + (bfhi(u2.y) + bfhi(u3.y));
  }
  for (; e < e1; e++) {
    uint2 u = Tw[(size_t)csr[e] * 16 + ql];
    a0 += bflo(u.x); a1 += bfhi(u.x); a2 += bflo(u.y); a3 += bfhi(u.y);
  }
  float4 rv = ((const float4*)resid)[(size_t)wid * 16 + ql];
  float v0 = di * a0 + bias[ql * 4];
  float v1 = di * a1 + bias[ql * 4 + 1];
  float v2 = di * a2 + bias[ql * 4 + 2];
  float v3 = di * a3 + bias[ql * 4 + 3];
  v0 = (v0 >= 0.f) ? v0 : 0.01f * v0;
  v1 = (v1 >= 0.f) ? v1 : 0.01f * v1;
  v2 = (v2 >= 0.f) ? v2 : 0.01f * v2;
  v3 = (v3 >= 0.f) ? v3 : 0.01f * v3;
  v0 += rv.x; v1 += rv.y; v2 += rv.z; v3 += rv.w;
  float s = (v0 + v1) + (v2 + v3);
  float ss = (v0 * v0 + v1 * v1) + (v2 * v2 + v3 * v3);
#pragma unroll
  for (int o = 8; o > 0; o >>= 1) {
    s += __shfl_xor(s, o);
    ss += __shfl_xor(ss, o);
  }
  float m = s * (1.f / 64.f);
  float var = ss * (1.f / 64.f) - m * m;
  float rs = rsqrtf(var + 1e-5f);
  float4 o4;
  o4.x = (v0 - m) * rs * g[ql * 4]     + b[ql * 4];
  o4.y = (v1 - m) * rs * g[ql * 4 + 1] + b[ql * 4 + 1];
  o4.z = (v2 - m) * rs * g[ql * 4 + 2] + b[ql * 4 + 2];
  o4.w = (v3 - m) * rs * g[ql * 4 + 3] + b[ql * 4 + 3];
  ((float4*)outh)[(size_t)wid * 16 + ql] = o4;
}

// 256-dim bf16 gather, quad-node: lane covers 16 features (32B = 2x bf16x8)
__global__ __launch_bounds__(256) void agg256b_k(const short* __restrict__ T, const float* __restrict__ dis,
                                                 const int* __restrict__ off, const int* __restrict__ csr,
                                                 short* __restrict__ Out, int n) {
  int wv = (blockIdx.x * 256 + threadIdx.x) >> 6;
  int lane = threadIdx.x & 63;
  int qtr = lane >> 4, ql = lane & 15;
  int wid = wv * 4 + qtr;
  if (wid >= n) return;
  float di = dis[wid];
  int e0 = off[wid], e1 = off[wid + 1];
  const short* base = T + (size_t)wid * 256 + ql * 16;
  bf16x8 s0 = *(const bf16x8*)base;
  bf16x8 s1 = *(const bf16x8*)(base + 8);
  float a[16];
#pragma unroll
  for (int q = 0; q < 8; q++) { a[q] = bf2f((unsigned short)s0[q]); a[8 + q] = bf2f((unsigned short)s1[q]); }
  int e = e0;
  for (; e + 4 <= e1; e += 4) {
    const short* p0 = T + (size_t)csr[e]     * 256 + ql * 16;
    const short* p1 = T + (size_t)csr[e + 1] * 256 + ql * 16;
    const short* p2 = T + (size_t)csr[e + 2] * 256 + ql * 16;
    const short* p3 = T + (size_t)csr[e + 3] * 256 + ql * 16;
    bf16x8 t00 = *(const bf16x8*)p0, t01 = *(const bf16x8*)(p0 + 8);
    bf16x8 t10 = *(const bf16x8*)p1, t11 = *(const bf16x8*)(p1 + 8);
    bf16x8 t20 = *(const bf16x8*)p2, t21 = *(const bf16x8*)(p2 + 8);
    bf16x8 t30 = *(const bf16x8*)p3, t31 = *(const bf16x8*)(p3 + 8);
#pragma unroll
    for (int q = 0; q < 8; q++) {
      a[q] += (bf2f((unsigned short)t00[q]) + bf2f((unsigned short)t10[q])) +
              (bf2f((unsigned short)t20[q]) + bf2f((unsigned short)t30[q]));
      a[8 + q] += (bf2f((unsigned short)t01[q]) + bf2f((unsigned short)t11[q])) +
                  (bf2f((unsigned short)t21[q]) + bf2f((unsigned short)t31[q]));
    }
  }
  for (; e < e1; e++) {
    const short* p = T + (size_t)csr[e] * 256 + ql * 16;
    bf16x8 t0 = *(const bf16x8*)p, t1 = *(const bf16x8*)(p + 8);
#pragma unroll
    for (int q = 0; q < 8; q++) {
      a[q] += bf2f((unsigned short)t0[q]);
      a[8 + q] += bf2f((unsigned short)t1[q]);
    }
  }
  bf16x8 o0, o1;
#pragma unroll
  for (int q = 0; q < 8; q++) {
    o0[q] = (short)f2bf(di * a[q]);
    o1[q] = (short)f2bf(di * a[8 + q]);
  }
  short* ob = Out + (size_t)wid * 256 + ql * 16;
  *(bf16x8*)ob = o0;
  *(bf16x8*)(ob + 8) = o1;
}

// ---------------- per-graph max pool + final MLP (fused, one block per graph) ----------------

__global__ __launch_bounds__(256) void pool_mlp_k(const float* __restrict__ hn,
                                                  const float* __restrict__ fc1W, const float* __restrict__ fc1b,
                                                  const float* __restrict__ fng, const float* __restrict__ fnb,
                                                  const float* __restrict__ fc2W, const float* __restrict__ fc2b,
                                                  float* __restrict__ out, int n) {
  const int G = 64;
  int g = blockIdx.x;
  int f = threadIdx.x & 63, c = threadIdx.x >> 6;
  long long s0 = ((long long)g * n + G - 1) / G;
  long long e0 = ((long long)(g + 1) * n + G - 1) / G;
  float m = -INFINITY;
  for (long long i = s0 + c; i < e0; i += 4) m = fmaxf(m, hn[(size_t)i * 64 + f]);
  __shared__ float red[4][64];
  __shared__ float ps[64], qs[64];
  red[c][f] = m;
  __syncthreads();
  if (c == 0) ps[f] = fmaxf(fmaxf(red[0][f], red[1][f]), fmaxf(red[2][f], red[3][f]));
  __syncthreads();
  if (threadIdx.x < 64) {
    int lane = threadIdx.x;
    float q = fc1b[lane];
#pragma unroll 8
    for (int k = 0; k < 64; k++) q = fmaf(ps[k], fc1W[k * 64 + lane], q);
    float s = q, ss = q * q;
#pragma unroll
    for (int o = 32; o > 0; o >>= 1) {
      s += __shfl_xor(s, o);
      ss += __shfl_xor(ss, o);
    }
    float mm = s * (1.f / 64.f);
    float var = ss * (1.f / 64.f) - mm * mm;
    float y = (q - mm) * rsqrtf(var + 1e-5f) * fng[lane] + fnb[lane];
    y = (y >= 0.f) ? y : 0.01f * y;
    qs[lane] = y;
    __builtin_amdgcn_wave_barrier();
    if (lane < 16) {
      float o = fc2b[lane];
#pragma unroll 8
      for (int k = 0; k < 64; k++) o = fmaf(qs[k], fc2W[k * 16 + lane], o);
      out[g * 16 + lane] = o;
    }
  }
}

// ---------------- launch ----------------

extern "C" void kernel_launch(void* const* d_in, const int* in_sizes, int n_in,
                              void* d_out, int out_size, void* d_ws, size_t ws_size,
                              hipStream_t stream) {
  const float* x   = (const float*)d_in[0];
  const int*   ei  = (const int*)d_in[1];
  const float* W1  = (const float*)d_in[3];
  const float* b1  = (const float*)d_in[4];
  const float* W2  = (const float*)d_in[5];
  const float* b2  = (const float*)d_in[6];
  const float* W3  = (const float*)d_in[7];
  const float* b3  = (const float*)d_in[8];
  const float* W4  = (const float*)d_in[9];
  const float* b4  = (const float*)d_in[10];
  const float* Wr  = (const float*)d_in[11];
  const float* br  = (const float*)d_in[12];
  const float* lng = (const float*)d_in[13];
  const float* lnb = (const float*)d_in[14];
  const float* f1W = (const float*)d_in[15];
  const float* f1b = (const float*)d_in[16];
  const float* fng = (const float*)d_in[17];
  const float* fnb = (const float*)d_in[18];
  const float* f2W = (const float*)d_in[19];
  const float* f2b = (const float*)d_in[20];

  int n = in_sizes[0] / 128;   // 50000
  int e = in_sizes[1] / 2;     // 400000
  const int* src = ei;
  const int* dst = ei + e;

  float* arena = (float*)d_ws;
  float* resid = arena;
  short* h2b   = (short*)(arena + (size_t)64 * n);
  short* t4b   = (short*)(arena + (size_t)64 * n);   // n x 64 bf16; h2b dead when written
  short* z3b   = (short*)(arena + (size_t)192 * n);
  float* hn    = arena + (size_t)192 * n;
  short* t1b   = (short*)(arena + (size_t)320 * n);
  short* h1b   = (short*)(arena + (size_t)352 * n);
  short* z2b   = (short*)(arena + (size_t)384 * n);
  float* dis   = arena + (size_t)448 * n;  // n
  int* cnt    = (int*)(dis + n);           // n
  int* off    = cnt + n;                   // n+1
  int* cursor = off + n + 1;               // n
  int* csr    = cursor + n;                // e
  int* bsum   = csr + e;                   // 256
  int* bpre   = bsum + 256;                // 256
  float* pool = (float*)(bpre + 256);      // layout keep
  size_t wq = (((size_t)(pool + 4096)) + 15) & ~(size_t)15;
  short* wc1 = (short*)wq;                 // 64 x 128   (wc1||wcR = fused 128 x 128)
  short* wcR = wc1 + 8192;                 // 64 x 128
  short* wc2 = wcR + 8192;                 // 256 x 64
  short* wc3 = wc2 + 16384;                // 512 x 256
  short* wc4 = wc3 + 131072;               // 64 x 512
  size_t need = ((char*)(wc4 + 32768) - (char*)d_ws) + 64;
  if (ws_size < need) return;

  int nb_n = (n + 255) / 256;        // 196
  int nb_e = (e + 255) / 256;
  int nb_w4 = ((n + 3) / 4 + 3) / 4; // four nodes per wave
  int g_wide = (n + 63) / 64;        // 782
  int g_fused = (n + 127) / 128;     // 391

  // weights -> bf16 [N][K]
  wconv_k<<<960, 256, 0, stream>>>(W1, Wr, W2, W3, W4, wc1, wcR, wc2, wc3, wc4);

  // degree + CSR (hierarchical scan; dis fused into scan_c)
  hipMemsetAsync(cnt, 0, (size_t)n * sizeof(int), stream);
  count_k<<<nb_e, 256, 0, stream>>>(dst, cnt, e);
  scan_a<<<nb_n, 256, 0, stream>>>(cnt, bsum, n);
  scan_b<<<1, 256, 0, stream>>>(bsum, bpre, off + n, nb_n);
  scan_c<<<nb_n, 256, 0, stream>>>(cnt, bpre, off, cursor, dis, n);
  scatter_k<<<nb_e, 256, 0, stream>>>(src, dst, cursor, csr, e);

  // fused L1 + residual: t1b = bf16(dis*(x@W1)); resid = x@Wr + br
  mgemm<128, 128, 2, 2, 1, 0, 0, 0, 1, 1, 4><<<dim3(g_fused, 1), 256, 0, stream>>>(x, wc1, br, t1b, resid, dis, n);
  // h1b = bf16( dis * leaky(di*sum(t1) + b1) )
  aggb64_k<1, 1><<<nb_w4, 256, 0, stream>>>(t1b, dis, off, csr, b1, h1b, n);
  // z2b = bf16( di * sum(h1) )
  aggb64_k<0, 0><<<nb_w4, 256, 0, stream>>>(h1b, dis, off, csr, nullptr, z2b, n);
  // h2b = bf16( dis * leaky(z2@W2 + b2) )
  mgemm<64, 256, 1, 4, 1, 1, 1, 1, 0, 1, 5><<<dim3(g_wide, 1), 256, 0, stream>>>(z2b, wc2, b2, h2b, nullptr, dis, n);
  // z3b = bf16( di * sum(h2b) )
  agg256b_k<<<nb_w4, 256, 0, stream>>>(h2b, dis, off, csr, z3b, n);
  // t4b = bf16( dis * (leaky(z3@W3+b3) @ W4) )   (h3 on-chip, ping-pong)
  fused34_k<<<g_wide, 256, 0, stream>>>(z3b, wc3, b3, wc4, dis, t4b, n);
  // hn = LN( leaky(di*sum(t4b) + b4) + resid )   (quad-node)
  agg64_ln_k<<<nb_w4, 256, 0, stream>>>(t4b, dis, off, csr, b4, resid, lng, lnb, hn, n);
  // pool + MLP fused
  pool_mlp_k<<<64, 256, 0, stream>>>(hn, f1W, f1b, fng, fnb, f2W, f2b, (float*)d_out, n);
}